// Round 11
// baseline (222.983 us; speedup 1.0000x reference)
//
#include <hip/hip_runtime.h>
#include <math.h>

#define N_USERS    100000
#define N_ENTITIES 200000
#define N_EDGES    1000000
#define NNZ        1000000
#define CDIM       64
#define N_FACTORS  4
#define N_REL      10
#define TEMP       0.2f

#define CB         1024
#define NBE        196      // ceil(200000/1024)
#define NBU        98       // ceil(100000/1024)
#define ACHUNK     4096
#define GA         245      // ceil(1e6/4096)
#define GCVT       6250     // (200000*64/8)/256
#define KG_WAVES   25000    // 200000 / 8
#define USER_WAVES 12500    // 100000 / 8
#define HOP_BLOCKS 9375     // (KG_WAVES + USER_WAVES) / 4
#define PCHUNK     4096
#define GPE        49       // ceil(200000/4096)
#define GPU_       25       // ceil(100000/4096)

typedef unsigned int u32;
typedef unsigned short u16;
typedef unsigned char u8;

#if defined(__has_builtin)
#if __has_builtin(__builtin_amdgcn_cvt_pk_f32_fp8) && __has_builtin(__builtin_amdgcn_cvt_pk_fp8_f32)
#define HAVE_HW_FP8 1
#endif
#endif

// ---- bf16 helpers ----------------------------------------------------------
__device__ __forceinline__ float bflo(u32 w) { return __uint_as_float(w << 16); }
__device__ __forceinline__ float bfhi(u32 w) { return __uint_as_float(w & 0xFFFF0000u); }
__device__ __forceinline__ u16 f2bf(float f) {
    u32 u = __float_as_uint(f);
    u32 r = u + 0x7FFFu + ((u >> 16) & 1u);   // RNE
    return (u16)(r >> 16);
}
__device__ __forceinline__ void unpack8_bf(uint4 rv, float* x) {
    x[0] = bflo(rv.x); x[1] = bfhi(rv.x);
    x[2] = bflo(rv.y); x[3] = bfhi(rv.y);
    x[4] = bflo(rv.z); x[5] = bfhi(rv.z);
    x[6] = bflo(rv.w); x[7] = bfhi(rv.w);
}
__device__ __forceinline__ uint4 pack8_bf(const float* x) {
    uint4 o;
    o.x = (u32)f2bf(x[0]) | ((u32)f2bf(x[1]) << 16);
    o.y = (u32)f2bf(x[2]) | ((u32)f2bf(x[3]) << 16);
    o.z = (u32)f2bf(x[4]) | ((u32)f2bf(x[5]) << 16);
    o.w = (u32)f2bf(x[6]) | ((u32)f2bf(x[7]) << 16);
    return o;
}

// ---- fp8 e4m3 helpers ------------------------------------------------------
#ifndef HAVE_HW_FP8
__device__ __forceinline__ float fp8_dec1(u32 b) {
    u32 s = b >> 7, em = b & 0x7F;
    float mag;
    if (em < 8) mag = (float)em * 0.001953125f;                      // subnormal, 2^-9
    else {
        u32 bits = (((em >> 3) + 120u) << 23) | ((em & 7u) << 20);
        mag = __uint_as_float(bits);
    }
    return s ? -mag : mag;
}
__device__ __forceinline__ u32 fp8_enc1(float f) {
    float a = fabsf(f);
    u32 s = (__float_as_uint(f) >> 31) << 7;
    if (a < 0.015625f) {
        int n = (int)rintf(a * 512.0f);                              // 0..8
        return s | (u32)n;
    }
    u32 u = __float_as_uint(a);
    u32 r = u + 0x0007FFFFu + ((u >> 20) & 1u);                      // RNE at bit 20
    int ee = (int)((r >> 23) & 0xFF) - 127 + 7;
    if (ee >= 16) return s | 0x7Eu;                                  // clamp to 448
    return s | ((u32)ee << 3) | ((r >> 20) & 7u);
}
#endif

__device__ __forceinline__ void unpack8_fp8(uint2 rv, float* x) {
#ifdef HAVE_HW_FP8
    typedef float floatx2 __attribute__((ext_vector_type(2)));
    floatx2 a0 = __builtin_amdgcn_cvt_pk_f32_fp8(rv.x, false);
    floatx2 a1 = __builtin_amdgcn_cvt_pk_f32_fp8(rv.x, true);
    floatx2 a2 = __builtin_amdgcn_cvt_pk_f32_fp8(rv.y, false);
    floatx2 a3 = __builtin_amdgcn_cvt_pk_f32_fp8(rv.y, true);
    x[0] = a0.x; x[1] = a0.y; x[2] = a1.x; x[3] = a1.y;
    x[4] = a2.x; x[5] = a2.y; x[6] = a3.x; x[7] = a3.y;
#else
    x[0] = fp8_dec1(rv.x & 0xFF);         x[1] = fp8_dec1((rv.x >> 8) & 0xFF);
    x[2] = fp8_dec1((rv.x >> 16) & 0xFF); x[3] = fp8_dec1(rv.x >> 24);
    x[4] = fp8_dec1(rv.y & 0xFF);         x[5] = fp8_dec1((rv.y >> 8) & 0xFF);
    x[6] = fp8_dec1((rv.y >> 16) & 0xFF); x[7] = fp8_dec1(rv.y >> 24);
#endif
}
__device__ __forceinline__ uint2 pack8_fp8(const float* x) {
    uint2 o;
#ifdef HAVE_HW_FP8
    int v0 = 0, v1 = 0;
    v0 = __builtin_amdgcn_cvt_pk_fp8_f32(x[0], x[1], v0, false);
    v0 = __builtin_amdgcn_cvt_pk_fp8_f32(x[2], x[3], v0, true);
    v1 = __builtin_amdgcn_cvt_pk_fp8_f32(x[4], x[5], v1, false);
    v1 = __builtin_amdgcn_cvt_pk_fp8_f32(x[6], x[7], v1, true);
    o.x = (u32)v0; o.y = (u32)v1;
#else
    o.x = fp8_enc1(x[0]) | (fp8_enc1(x[1]) << 8) | (fp8_enc1(x[2]) << 16) | (fp8_enc1(x[3]) << 24);
    o.y = fp8_enc1(x[4]) | (fp8_enc1(x[5]) << 8) | (fp8_enc1(x[6]) << 16) | (fp8_enc1(x[7]) << 24);
#endif
    return o;
}

__device__ __forceinline__ void fma_rowW(float* acc, uint2 rv, int rel,
                                         const float* __restrict__ weight, int seg) {
    float x[8]; unpack8_fp8(rv, x);
    const float4* wp = (const float4*)(weight + rel * CDIM + seg * 8);
    float4 w0 = wp[0], w1 = wp[1];
    acc[0] += x[0] * w0.x; acc[1] += x[1] * w0.y;
    acc[2] += x[2] * w0.z; acc[3] += x[3] * w0.w;
    acc[4] += x[4] * w1.x; acc[5] += x[5] * w1.y;
    acc[6] += x[6] * w1.z; acc[7] += x[7] * w1.w;
}
__device__ __forceinline__ void fma_rowV(float* acc, uint2 rv, float v) {
    float x[8]; unpack8_fp8(rv, x);
    #pragma unroll
    for (int k = 0; k < 8; ++k) acc[k] += v * x[k];
}

// in-LDS exclusive scan of a 256-entry histogram; sbase[t] = excl, returns via LDS
__device__ __forceinline__ void lds_scan256(const int* __restrict__ hist, int* sbase,
                                            int* stmp) {
    int t = threadIdx.x;
    int v = hist[t];
    stmp[t] = v; __syncthreads();
    #pragma unroll
    for (int d = 1; d < 256; d <<= 1) {
        int x = (t >= d) ? stmp[t - d] : 0;
        __syncthreads();
        stmp[t] += x;
        __syncthreads();
    }
    sbase[t] = stmp[t] - v;
    __syncthreads();
}

// ============ kernel A: cvt(f32->fp8) + 2x coarse hist + disen/cor ===========
__device__ void dev_cvt(int b, const float* __restrict__ in, u8* __restrict__ out) {
    int i = b * 256 + threadIdx.x;
    const float4* p = (const float4*)(in + (size_t)i * 8);
    float4 a = p[0], bb = p[1];
    float x[8] = {a.x, a.y, a.z, a.w, bb.x, bb.y, bb.z, bb.w};
    *(uint2*)(out + (size_t)i * 8) = pack8_fp8(x);
}

__device__ void dev_coarse_hist(int b, const int* __restrict__ idx, int n,
                                int* __restrict__ bhist) {
    __shared__ int lh[256];
    int t = threadIdx.x;
    lh[t] = 0; __syncthreads();
    int base = b * ACHUNK;
    #pragma unroll
    for (int k = 0; k < 16; ++k) {
        int i = base + k * 256 + t;
        if (i < n) atomicAdd(&lh[idx[i] >> 10], 1);
    }
    __syncthreads();
    if (lh[t]) atomicAdd(&bhist[t], lh[t]);
}

__device__ void dev_disen_cor(const float* __restrict__ att,
                              const float* __restrict__ weight,
                              float* __restrict__ dw, float* __restrict__ cor_out) {
    int tid = threadIdx.x;
    int f = tid >> 6, c = tid & 63;
    float m = -1e30f;
    for (int r = 0; r < N_REL; ++r) m = fmaxf(m, att[f * N_REL + r]);
    float e[N_REL], s = 0.0f;
    for (int r = 0; r < N_REL; ++r) { e[r] = __expf(att[f * N_REL + r] - m); s += e[r]; }
    float acc = 0.0f;
    for (int r = 0; r < N_REL; ++r) acc += (e[r] / s) * weight[r * CDIM + c];
    dw[f * CDIM + c] = acc;

    if (tid == 0) {
        float rowsum[N_FACTORS];
        for (int ff = 0; ff < N_FACTORS; ++ff) {
            float ss = 0.0f;
            for (int j = 0; j < N_REL; ++j) ss += att[ff * N_REL + j];
            rowsum[ff] = ss;
        }
        float cor = 0.0f;
        for (int i = 0; i < N_REL; ++i) {
            float nsq = 0.0f, ttl = 0.0f;
            for (int ff = 0; ff < N_FACTORS; ++ff) {
                float a = att[ff * N_REL + i];
                nsq += a * a;
                ttl += a * rowsum[ff];
            }
            float n = sqrtf(nsq);
            float pos = 0.0f;
            for (int ff = 0; ff < N_FACTORS; ++ff) {
                float a = att[ff * N_REL + i] / n;
                pos += a * a;
            }
            cor += (ttl - pos) / TEMP;
        }
        *cor_out = cor;
    }
}

__global__ __launch_bounds__(256) void prep_kernel(const float* __restrict__ entity_emb,
                                                   u8* __restrict__ ef8,
                                                   const int* __restrict__ head,
                                                   const int* __restrict__ inter_rows,
                                                   int* __restrict__ bhe,
                                                   int* __restrict__ bhu,
                                                   const float* __restrict__ att,
                                                   const float* __restrict__ weight,
                                                   float* __restrict__ dw,
                                                   float* __restrict__ cor_out) {
    int bid = blockIdx.x;
    if (bid < GCVT)                 dev_cvt(bid, entity_emb, ef8);
    else if (bid < GCVT + GA)       dev_coarse_hist(bid - GCVT, head, N_EDGES, bhe);
    else if (bid < GCVT + 2 * GA)   dev_coarse_hist(bid - GCVT - GA, inter_rows, NNZ, bhu);
    else                            dev_disen_cor(att, weight, dw, cor_out);
}

// ============ kernel B: bin passes (in-block scan of bhist + zcur reserve) ===
__device__ void dev_bin_edges(int b, const int* __restrict__ head,
                              const int* __restrict__ tail, const int* __restrict__ etype,
                              const int* __restrict__ bhist,
                              int* __restrict__ zcur, int* __restrict__ binbuf) {
    __shared__ int sbase[256], stmp[256];
    __shared__ int lh[256], lbase[256];
    int t = threadIdx.x;
    lds_scan256(bhist, sbase, stmp);
    lh[t] = 0; __syncthreads();
    int base = b * ACHUNK;
    int rec[16], rnk[16], bkt[16];
    #pragma unroll
    for (int k = 0; k < 16; ++k) {
        int i = base + k * 256 + t;
        rnk[k] = -1; rec[k] = 0; bkt[k] = 0;
        if (i < N_EDGES) {
            int h = head[i];
            bkt[k] = h >> 10;
            rec[k] = ((h & 1023) << 22) | ((etype[i] - 1) << 18) | tail[i];
            rnk[k] = atomicAdd(&lh[bkt[k]], 1);
        }
    }
    __syncthreads();
    lbase[t] = lh[t] ? (sbase[t] + atomicAdd(&zcur[t], lh[t])) : 0;
    __syncthreads();
    #pragma unroll
    for (int k = 0; k < 16; ++k)
        if (rnk[k] >= 0) binbuf[lbase[bkt[k]] + rnk[k]] = rec[k];
}

__device__ void dev_bin_inter(int b, const int* __restrict__ rows,
                              const int* __restrict__ cols, const float* __restrict__ vals,
                              const int* __restrict__ bhist,
                              int* __restrict__ zcur, int2* __restrict__ binbuf) {
    __shared__ int sbase[256], stmp[256];
    __shared__ int lh[256], lbase[256];
    int t = threadIdx.x;
    lds_scan256(bhist, sbase, stmp);
    lh[t] = 0; __syncthreads();
    int base = b * ACHUNK;
    int recx[16], recy[16], rnk[16], bkt[16];
    #pragma unroll
    for (int k = 0; k < 16; ++k) {
        int i = base + k * 256 + t;
        rnk[k] = -1; recx[k] = 0; recy[k] = 0; bkt[k] = 0;
        if (i < NNZ) {
            int r = rows[i];
            bkt[k] = r >> 10;
            recx[k] = ((r & 1023) << 18) | cols[i];
            recy[k] = __float_as_int(vals[i]);
            rnk[k] = atomicAdd(&lh[bkt[k]], 1);
        }
    }
    __syncthreads();
    lbase[t] = lh[t] ? (sbase[t] + atomicAdd(&zcur[t], lh[t])) : 0;
    __syncthreads();
    #pragma unroll
    for (int k = 0; k < 16; ++k)
        if (rnk[k] >= 0) {
            int2 p; p.x = recx[k]; p.y = recy[k];
            binbuf[lbase[bkt[k]] + rnk[k]] = p;
        }
}

__global__ __launch_bounds__(256) void bin_kernel(const int* __restrict__ head,
                                                  const int* __restrict__ tail,
                                                  const int* __restrict__ etype,
                                                  const int* __restrict__ rows,
                                                  const int* __restrict__ cols,
                                                  const float* __restrict__ vals,
                                                  const int* __restrict__ bhe,
                                                  const int* __restrict__ bhu,
                                                  int* __restrict__ zce, int* __restrict__ zcu,
                                                  int* __restrict__ bine, int2* __restrict__ binu) {
    int bid = blockIdx.x;
    if (bid < GA) dev_bin_edges(bid, head, tail, etype, bhe, zce, bine);
    else          dev_bin_inter(bid - GA, rows, cols, vals, bhu, zcu, binu);
}

// ============ kernel C: per-bucket CSR finalize + degree histogram ===========
__device__ void dev_build_e(int b, const int* __restrict__ bhist,
                            const int* __restrict__ binbuf,
                            int* __restrict__ eoff, int* __restrict__ epk,
                            int* __restrict__ dbinE) {
    __shared__ int sbase[256], stmp[256];
    __shared__ int lh[CB];
    __shared__ int ss[256];
    __shared__ int ldeg[64];
    int t = threadIdx.x;
    lds_scan256(bhist, sbase, stmp);
    int bstart = sbase[b], bend = sbase[b] + bhist[b];
    #pragma unroll
    for (int k = 0; k < 4; ++k) lh[t * 4 + k] = 0;
    if (t < 64) ldeg[t] = 0;
    __syncthreads();
    for (int j = bstart + t; j < bend; j += 256)
        atomicAdd(&lh[(u32)binbuf[j] >> 22], 1);
    __syncthreads();
    int v[4], acc = 0;
    #pragma unroll
    for (int k = 0; k < 4; ++k) { v[k] = lh[t * 4 + k]; acc += v[k]; }
    ss[t] = acc; __syncthreads();
    #pragma unroll
    for (int d = 1; d < 256; d <<= 1) {
        int x = (t >= d) ? ss[t - d] : 0;
        __syncthreads();
        ss[t] += x;
        __syncthreads();
    }
    int excl = ss[t] - acc;
    int hbase = b * CB;
    #pragma unroll
    for (int k = 0; k < 4; ++k) {
        int hl = t * 4 + k;
        int h = hbase + hl;
        if (h < N_ENTITIES) {
            eoff[h] = bstart + excl;
            atomicAdd(&ldeg[63 - min(v[k], 63)], 1);   // descending-degree bins
        }
        lh[hl] = excl;
        excl += v[k];
    }
    __syncthreads();
    if (t < 64 && ldeg[t]) atomicAdd(&dbinE[t], ldeg[t]);
    if (b == 0 && t == 0) eoff[N_ENTITIES] = N_EDGES;
    for (int j = bstart + t; j < bend; j += 256) {
        int rec = binbuf[j];
        int pos = atomicAdd(&lh[(u32)rec >> 22], 1);
        epk[bstart + pos] = rec & 0x3FFFFF;   // rel<<18 | tail
    }
}

__device__ void dev_build_u(int b, const int* __restrict__ bhist,
                            const int2* __restrict__ binbuf,
                            int* __restrict__ uoff, int2* __restrict__ ucv,
                            int* __restrict__ dbinU) {
    __shared__ int sbase[256], stmp[256];
    __shared__ int lh[CB];
    __shared__ int ss[256];
    __shared__ int ldeg[64];
    int t = threadIdx.x;
    lds_scan256(bhist, sbase, stmp);
    int bstart = sbase[b], bend = sbase[b] + bhist[b];
    #pragma unroll
    for (int k = 0; k < 4; ++k) lh[t * 4 + k] = 0;
    if (t < 64) ldeg[t] = 0;
    __syncthreads();
    for (int j = bstart + t; j < bend; j += 256)
        atomicAdd(&lh[(u32)binbuf[j].x >> 18], 1);
    __syncthreads();
    int v[4], acc = 0;
    #pragma unroll
    for (int k = 0; k < 4; ++k) { v[k] = lh[t * 4 + k]; acc += v[k]; }
    ss[t] = acc; __syncthreads();
    #pragma unroll
    for (int d = 1; d < 256; d <<= 1) {
        int x = (t >= d) ? ss[t - d] : 0;
        __syncthreads();
        ss[t] += x;
        __syncthreads();
    }
    int excl = ss[t] - acc;
    int ubase = b * CB;
    #pragma unroll
    for (int k = 0; k < 4; ++k) {
        int ul = t * 4 + k;
        int u = ubase + ul;
        if (u < N_USERS) {
            uoff[u] = bstart + excl;
            atomicAdd(&ldeg[63 - min(v[k], 63)], 1);
        }
        lh[ul] = excl;
        excl += v[k];
    }
    __syncthreads();
    if (t < 64 && ldeg[t]) atomicAdd(&dbinU[t], ldeg[t]);
    if (b == 0 && t == 0) uoff[N_USERS] = NNZ;
    for (int j = bstart + t; j < bend; j += 256) {
        int2 rec = binbuf[j];
        int pos = atomicAdd(&lh[(u32)rec.x >> 18], 1);
        int2 out; out.x = rec.x & 0x3FFFF; out.y = rec.y;
        ucv[bstart + pos] = out;
    }
}

__global__ __launch_bounds__(256) void build_kernel(const int* __restrict__ bhe,
                                                    const int* __restrict__ bhu,
                                                    const int* __restrict__ bine,
                                                    const int2* __restrict__ binu,
                                                    int* __restrict__ eoff, int* __restrict__ epk,
                                                    int* __restrict__ uoff, int2* __restrict__ ucv,
                                                    int* __restrict__ dbinE, int* __restrict__ dbinU) {
    int bid = blockIdx.x;
    if (bid < NBE) dev_build_e(bid, bhe, bine, eoff, epk, dbinE);
    else           dev_build_u(bid - NBE, bhu, binu, uoff, ucv, dbinU);
}

// ============ kernel D: degree-sorted permutation (in-block deg scan) ========
__device__ void dev_perm(int b, int n, const int* __restrict__ off,
                         const int* __restrict__ dbin,
                         int* __restrict__ zdeg, int2* __restrict__ perm) {
    __shared__ int dbase[64], dtmp[64];
    __shared__ int lh[64], lbase[64];
    int t = threadIdx.x;
    if (t < 64) { dtmp[t] = dbin[t]; lh[t] = 0; }
    __syncthreads();
    if (t < 64) {
        int v = dtmp[t];
        // serial-ish scan over 64 by thread 0 would serialize; do simple Hillis-Steele
        #pragma unroll
        for (int d = 1; d < 64; d <<= 1) {
            int x = (t >= d) ? dtmp[t - d] : 0;
            __syncthreads();
            dtmp[t] += x;
            __syncthreads();
        }
        dbase[t] = dtmp[t] - v;
    } else {
        #pragma unroll
        for (int d = 1; d < 64; d <<= 1) { __syncthreads(); __syncthreads(); }
    }
    __syncthreads();
    int base = b * PCHUNK;
    int rnk[16], bin[16], deg[16], st[16];
    #pragma unroll
    for (int k = 0; k < 16; ++k) {
        int i = base + k * 256 + t;
        rnk[k] = -1;
        if (i < n) {
            int s0 = off[i], s1 = off[i + 1];
            deg[k] = s1 - s0; st[k] = s0;
            bin[k] = 63 - min(deg[k], 63);     // descending degree
            rnk[k] = atomicAdd(&lh[bin[k]], 1);
        }
    }
    __syncthreads();
    if (t < 64) lbase[t] = lh[t] ? (dbase[t] + atomicAdd(&zdeg[t], lh[t])) : 0;
    __syncthreads();
    #pragma unroll
    for (int k = 0; k < 16; ++k)
        if (rnk[k] >= 0) {
            int i = base + k * 256 + t;
            int2 p;
            p.x = (int)(((u32)min(deg[k], 16383) << 18) | (u32)i);
            p.y = st[k];
            perm[lbase[bin[k]] + rnk[k]] = p;
        }
}

__global__ __launch_bounds__(256) void perm_kernel(const int* __restrict__ eoff,
                                                   const int* __restrict__ uoff,
                                                   const int* __restrict__ dbinE,
                                                   const int* __restrict__ dbinU,
                                                   int* __restrict__ zdegE, int* __restrict__ zdegU,
                                                   int2* __restrict__ permE, int2* __restrict__ permU) {
    int bid = blockIdx.x;
    if (bid < GPE) dev_perm(bid, N_ENTITIES, eoff, dbinE, zdegE, permE);
    else           dev_perm(bid - GPE, N_USERS, uoff, dbinU, zdegU, permU);
}

// ============ hop kernels (kg + user interleaved), 8-deep pipelined gather ===
__device__ void dev_kg_hop(int widg, const u8* __restrict__ esrc,
                           const int2* __restrict__ permE,
                           const int* __restrict__ epk,
                           const float* __restrict__ weight,
                           const float* __restrict__ emb0,
                           u8* __restrict__ enew, float* __restrict__ eres, int last) {
    int lane = threadIdx.x & 63;
    int slot = lane >> 3, seg = lane & 7;
    int2 pe = permE[widg * 8 + slot];
    u32 px = (u32)pe.x;
    int d = px >> 18, h = (int)(px & 0x3FFFFu), s = pe.y;
    int dmax = d;
    dmax = max(dmax, __shfl_xor(dmax, 8, 64));
    dmax = max(dmax, __shfl_xor(dmax, 16, 64));
    dmax = max(dmax, __shfl_xor(dmax, 32, 64));

    float acc[8];
    #pragma unroll
    for (int k = 0; k < 8; ++k) acc[k] = 0.0f;
    const uint2 uz = make_uint2(0u, 0u);

    for (int it = 0; it < dmax; it += 8) {
        int pk[8]; uint2 rv[8];
        #pragma unroll
        for (int q = 0; q < 8; ++q)
            pk[q] = (it + q < d) ? epk[s + it + q] : 0;
        #pragma unroll
        for (int q = 0; q < 8; ++q)
            rv[q] = (it + q < d)
                  ? *(const uint2*)(esrc + (size_t)(pk[q] & 0x3FFFF) * CDIM + seg * 8) : uz;
        #pragma unroll
        for (int q = 0; q < 8; ++q)
            fma_rowW(acc, rv[q], pk[q] >> 18, weight, seg);
    }
    float inv = 1.0f / fmaxf((float)d, 1.0f);
    float ssq = 0.0f;
    #pragma unroll
    for (int k = 0; k < 8; ++k) { acc[k] *= inv; ssq += acc[k] * acc[k]; }
    ssq += __shfl_xor(ssq, 1, 64);
    ssq += __shfl_xor(ssq, 2, 64);
    ssq += __shfl_xor(ssq, 4, 64);
    float rn = 1.0f / fmaxf(sqrtf(ssq), 1e-12f);
    #pragma unroll
    for (int k = 0; k < 8; ++k) acc[k] *= rn;

    size_t base = (size_t)h * CDIM + seg * 8;
    if (!last) {
        *(uint2*)(enew + base) = pack8_fp8(acc);
    } else {
        uint2 pv = *(const uint2*)(esrc + base);   // esrc == hop0 output eA (fp8)
        float o0[8]; unpack8_fp8(pv, o0);
        float4 a = *(const float4*)(emb0 + base);
        float4 b = *(const float4*)(emb0 + base + 4);
        float4 r0, r1;
        r0.x = a.x + o0[0] + acc[0]; r0.y = a.y + o0[1] + acc[1];
        r0.z = a.z + o0[2] + acc[2]; r0.w = a.w + o0[3] + acc[3];
        r1.x = b.x + o0[4] + acc[4]; r1.y = b.y + o0[5] + acc[5];
        r1.z = b.z + o0[6] + acc[6]; r1.w = b.w + o0[7] + acc[7];
        *(float4*)(eres + base) = r0;
        *(float4*)(eres + base + 4) = r1;
    }
}

__device__ void dev_user_hop(int widg, const float* __restrict__ uoldf,
                             const u16* __restrict__ uoldb,
                             const u8* __restrict__ esrc,
                             const int2* __restrict__ permU,
                             const int2* __restrict__ ucv,
                             const float* __restrict__ latent,
                             const float* __restrict__ dw,
                             const float* __restrict__ uemb0,
                             u16* __restrict__ unew, float* __restrict__ ures, int last) {
    int lane = threadIdx.x & 63;
    int slot = lane >> 3, seg = lane & 7;
    int2 pe = permU[widg * 8 + slot];
    u32 px = (u32)pe.x;
    int d = px >> 18, u = (int)(px & 0x3FFFFu), s = pe.y;
    int dmax = d;
    dmax = max(dmax, __shfl_xor(dmax, 8, 64));
    dmax = max(dmax, __shfl_xor(dmax, 16, 64));
    dmax = max(dmax, __shfl_xor(dmax, 32, 64));

    float acc[8];
    #pragma unroll
    for (int k = 0; k < 8; ++k) acc[k] = 0.0f;
    const uint2 uz = make_uint2(0u, 0u);
    const int2 cz = make_int2(0, 0);

    for (int it = 0; it < dmax; it += 8) {
        int2 cc[8]; uint2 rv[8];
        #pragma unroll
        for (int q = 0; q < 8; ++q)
            cc[q] = (it + q < d) ? ucv[s + it + q] : cz;
        #pragma unroll
        for (int q = 0; q < 8; ++q)
            rv[q] = (it + q < d)
                  ? *(const uint2*)(esrc + (size_t)cc[q].x * CDIM + seg * 8) : uz;
        #pragma unroll
        for (int q = 0; q < 8; ++q)
            fma_rowV(acc, rv[q], __int_as_float(cc[q].y));
    }

    float uo[8];
    size_t ubase = (size_t)u * CDIM + seg * 8;
    if (uoldb) {
        uint4 pv = *(const uint4*)(uoldb + ubase);
        unpack8_bf(pv, uo);
    } else {
        float4 a = *(const float4*)(uoldf + ubase);
        float4 b = *(const float4*)(uoldf + ubase + 4);
        uo[0] = a.x; uo[1] = a.y; uo[2] = a.z; uo[3] = a.w;
        uo[4] = b.x; uo[5] = b.y; uo[6] = b.z; uo[7] = b.w;
    }
    float dts[N_FACTORS];
    #pragma unroll
    for (int f = 0; f < N_FACTORS; ++f) {
        const float4* lp = (const float4*)(latent + f * CDIM + seg * 8);
        float4 l0 = lp[0], l1 = lp[1];
        float p = uo[0] * l0.x + uo[1] * l0.y + uo[2] * l0.z + uo[3] * l0.w +
                  uo[4] * l1.x + uo[5] * l1.y + uo[6] * l1.z + uo[7] * l1.w;
        p += __shfl_xor(p, 1, 64);
        p += __shfl_xor(p, 2, 64);
        p += __shfl_xor(p, 4, 64);
        dts[f] = p;
    }
    float m = fmaxf(fmaxf(dts[0], dts[1]), fmaxf(dts[2], dts[3]));
    float e0 = __expf(dts[0] - m), e1 = __expf(dts[1] - m);
    float e2 = __expf(dts[2] - m), e3 = __expf(dts[3] - m);
    float inv_ssum = 1.0f / (e0 + e1 + e2 + e3);
    e0 *= inv_ssum; e1 *= inv_ssum; e2 *= inv_ssum; e3 *= inv_ssum;

    const float4* d0p = (const float4*)(dw + 0 * CDIM + seg * 8);
    const float4* d1p = (const float4*)(dw + 1 * CDIM + seg * 8);
    const float4* d2p = (const float4*)(dw + 2 * CDIM + seg * 8);
    const float4* d3p = (const float4*)(dw + 3 * CDIM + seg * 8);
    float4 ga0 = d0p[0], ga1 = d0p[1];
    float4 gb0 = d1p[0], gb1 = d1p[1];
    float4 gc0 = d2p[0], gc1 = d2p[1];
    float4 gd0 = d3p[0], gd1 = d3p[1];
    float g[8];
    g[0] = e0 * ga0.x + e1 * gb0.x + e2 * gc0.x + e3 * gd0.x;
    g[1] = e0 * ga0.y + e1 * gb0.y + e2 * gc0.y + e3 * gd0.y;
    g[2] = e0 * ga0.z + e1 * gb0.z + e2 * gc0.z + e3 * gd0.z;
    g[3] = e0 * ga0.w + e1 * gb0.w + e2 * gc0.w + e3 * gd0.w;
    g[4] = e0 * ga1.x + e1 * gb1.x + e2 * gc1.x + e3 * gd1.x;
    g[5] = e0 * ga1.y + e1 * gb1.y + e2 * gc1.y + e3 * gd1.y;
    g[6] = e0 * ga1.z + e1 * gb1.z + e2 * gc1.z + e3 * gd1.z;
    g[7] = e0 * ga1.w + e1 * gb1.w + e2 * gc1.w + e3 * gd1.w;

    float ssq = 0.0f;
    #pragma unroll
    for (int k = 0; k < 8; ++k) {
        acc[k] = acc[k] * (1.0f + g[k]);
        ssq += acc[k] * acc[k];
    }
    ssq += __shfl_xor(ssq, 1, 64);
    ssq += __shfl_xor(ssq, 2, 64);
    ssq += __shfl_xor(ssq, 4, 64);
    float rn = 1.0f / fmaxf(sqrtf(ssq), 1e-12f);
    #pragma unroll
    for (int k = 0; k < 8; ++k) acc[k] *= rn;

    if (!last) {
        *(uint4*)(unew + ubase) = pack8_bf(acc);
    } else {
        float4 a = *(const float4*)(uemb0 + ubase);
        float4 b = *(const float4*)(uemb0 + ubase + 4);
        float4 r0, r1;
        r0.x = a.x + uo[0] + acc[0]; r0.y = a.y + uo[1] + acc[1];
        r0.z = a.z + uo[2] + acc[2]; r0.w = a.w + uo[3] + acc[3];
        r1.x = b.x + uo[4] + acc[4]; r1.y = b.y + uo[5] + acc[5];
        r1.z = b.z + uo[6] + acc[6]; r1.w = b.w + uo[7] + acc[7];
        *(float4*)(ures + ubase) = r0;
        *(float4*)(ures + ubase + 4) = r1;
    }
}

__global__ __launch_bounds__(256) void hop_kernel(const u8* __restrict__ e_src,
                                                  const int2* __restrict__ permE,
                                                  const int* __restrict__ epk,
                                                  const float* __restrict__ weight,
                                                  const float* __restrict__ entity_emb,
                                                  u8* __restrict__ eA,
                                                  float* __restrict__ eres,
                                                  const float* __restrict__ uoldf,
                                                  const u16* __restrict__ uoldb,
                                                  const int2* __restrict__ permU,
                                                  const int2* __restrict__ ucv,
                                                  const float* __restrict__ latent,
                                                  const float* __restrict__ dw,
                                                  const float* __restrict__ user_emb,
                                                  u16* __restrict__ uA,
                                                  float* __restrict__ ures,
                                                  int last) {
    int bid = blockIdx.x;
    int wave = threadIdx.x >> 6;
    // interleave: every 3rd block is a user block (1:2 ratio = 3125:6250)
    if (bid % 3 == 0) {
        dev_user_hop((bid / 3) * 4 + wave, uoldf, uoldb, e_src, permU, ucv,
                     latent, dw, user_emb, uA, ures, last);
    } else {
        int kb = bid - bid / 3 - 1;
        dev_kg_hop(kb * 4 + wave, e_src, permE, epk, weight, entity_emb, eA, eres, last);
    }
}

static inline size_t align16(size_t x) { return (x + 15) & ~(size_t)15; }

extern "C" void kernel_launch(void* const* d_in, const int* in_sizes, int n_in,
                              void* d_out, int out_size, void* d_ws, size_t ws_size,
                              hipStream_t stream) {
    const float* user_emb   = (const float*)d_in[0];
    const float* entity_emb = (const float*)d_in[1];
    const float* latent_emb = (const float*)d_in[2];
    const float* weight     = (const float*)d_in[3];
    const float* att        = (const float*)d_in[4];
    const int*   edge_index = (const int*)d_in[5];
    const int*   edge_type  = (const int*)d_in[6];
    const int*   inter_rows = (const int*)d_in[7];
    const int*   inter_cols = (const int*)d_in[8];
    const float* inter_vals = (const float*)d_in[9];

    float* eres = (float*)d_out;
    float* ures = eres + (size_t)N_ENTITIES * CDIM;
    float* cor  = ures + (size_t)N_USERS * CDIM;

    char* ws = (char*)d_ws;
    u8*    ef8   = (u8*)ws;   ws += align16(sizeof(u8) * (size_t)N_ENTITIES * CDIM);
    u8*    eA    = (u8*)ws;   ws += align16(sizeof(u8) * (size_t)N_ENTITIES * CDIM);
    u16*   uA    = (u16*)ws;  ws += align16(sizeof(u16) * (size_t)N_USERS * CDIM);
    int*   eoff  = (int*)ws;  ws += align16(sizeof(int) * (N_ENTITIES + 1));
    int*   epk   = (int*)ws;  ws += align16(sizeof(int) * N_EDGES);
    int*   uoff  = (int*)ws;  ws += align16(sizeof(int) * (N_USERS + 1));
    int2*  ucv   = (int2*)ws; ws += align16(sizeof(int2) * NNZ);
    int*   bine  = (int*)ws;  ws += align16(sizeof(int) * N_EDGES);
    int2*  binu  = (int2*)ws; ws += align16(sizeof(int2) * NNZ);
    int*   ctrs  = (int*)ws;  ws += align16(sizeof(int) * 1280);
    int2*  permE = (int2*)ws; ws += align16(sizeof(int2) * N_ENTITIES);
    int2*  permU = (int2*)ws; ws += align16(sizeof(int2) * N_USERS);
    float* dw    = (float*)ws; ws += align16(sizeof(float) * N_FACTORS * CDIM);

    // counter layout (single 5 KB memset zeroes everything)
    int* bhe   = ctrs;          // 256: coarse hist entity
    int* bhu   = ctrs + 256;    // 256: coarse hist user
    int* dbinE = ctrs + 512;    // 64:  degree-bin hist entity
    int* dbinU = ctrs + 576;    // 64:  degree-bin hist user
    int* zce   = ctrs + 640;    // 256: bin-pass reservation cursors (entity)
    int* zcu   = ctrs + 896;    // 256: bin-pass reservation cursors (user)
    int* zdegE = ctrs + 1152;   // 64:  perm reservation cursors (entity)
    int* zdegU = ctrs + 1216;   // 64:  perm reservation cursors (user)

    const int* head = edge_index;
    const int* tail = edge_index + N_EDGES;

    (void)hipMemsetAsync(ctrs, 0, sizeof(int) * 1280, stream);

    prep_kernel<<<GCVT + 2 * GA + 1, 256, 0, stream>>>(entity_emb, ef8, head, inter_rows,
                                                       bhe, bhu, att, weight, dw, cor);
    bin_kernel<<<2 * GA, 256, 0, stream>>>(head, tail, edge_type,
                                           inter_rows, inter_cols, inter_vals,
                                           bhe, bhu, zce, zcu, bine, binu);
    build_kernel<<<NBE + NBU, 256, 0, stream>>>(bhe, bhu, bine, binu,
                                                eoff, epk, uoff, ucv, dbinE, dbinU);
    perm_kernel<<<GPE + GPU_, 256, 0, stream>>>(eoff, uoff, dbinE, dbinU,
                                                zdegE, zdegU, permE, permU);

    // hop 0: gather from ef8; write fp8 eA + bf16 uA
    hop_kernel<<<HOP_BLOCKS, 256, 0, stream>>>(
        ef8, permE, epk, weight, entity_emb, eA, eres,
        user_emb, (const u16*)nullptr, permU, ucv, latent_emb, dw, user_emb, uA, ures, 0);
    // hop 1: gather from eA; write res = emb0 + o0 + o1
    hop_kernel<<<HOP_BLOCKS, 256, 0, stream>>>(
        eA, permE, epk, weight, entity_emb, (u8*)nullptr, eres,
        (const float*)nullptr, uA, permU, ucv, latent_emb, dw, user_emb, (u16*)nullptr, ures, 1);
}

// Round 12
// 219.894 us; speedup vs baseline: 1.0140x; 1.0140x over previous
//
#include <hip/hip_runtime.h>
#include <math.h>

#define N_USERS    100000
#define N_ENTITIES 200000
#define N_EDGES    1000000
#define NNZ        1000000
#define CDIM       64
#define N_FACTORS  4
#define N_REL      10
#define TEMP       0.2f

#define CB         1024
#define NBE        196      // ceil(200000/1024)
#define NBU        98       // ceil(100000/1024)
#define ACHUNK     4096
#define GA         245      // ceil(1e6/4096)
#define GCVT       6250     // (200000*64/8)/256
#define KG_BLOCKS  6250     // 200000 / 32 rows per block
#define USER_BLOCKS 3125    // 100000 / 32
#define PCHUNK     4096
#define GPE        49       // ceil(200000/4096)
#define GPU_       25       // ceil(100000/4096)

typedef unsigned int u32;
typedef unsigned short u16;
typedef unsigned char u8;

#if defined(__has_builtin)
#if __has_builtin(__builtin_amdgcn_cvt_pk_f32_fp8) && __has_builtin(__builtin_amdgcn_cvt_pk_fp8_f32)
#define HAVE_HW_FP8 1
#endif
#endif

// ---- bf16 helpers ----------------------------------------------------------
__device__ __forceinline__ float bflo(u32 w) { return __uint_as_float(w << 16); }
__device__ __forceinline__ float bfhi(u32 w) { return __uint_as_float(w & 0xFFFF0000u); }
__device__ __forceinline__ u16 f2bf(float f) {
    u32 u = __float_as_uint(f);
    u32 r = u + 0x7FFFu + ((u >> 16) & 1u);   // RNE
    return (u16)(r >> 16);
}
__device__ __forceinline__ void unpack8_bf(uint4 rv, float* x) {
    x[0] = bflo(rv.x); x[1] = bfhi(rv.x);
    x[2] = bflo(rv.y); x[3] = bfhi(rv.y);
    x[4] = bflo(rv.z); x[5] = bfhi(rv.z);
    x[6] = bflo(rv.w); x[7] = bfhi(rv.w);
}
__device__ __forceinline__ uint4 pack8_bf(const float* x) {
    uint4 o;
    o.x = (u32)f2bf(x[0]) | ((u32)f2bf(x[1]) << 16);
    o.y = (u32)f2bf(x[2]) | ((u32)f2bf(x[3]) << 16);
    o.z = (u32)f2bf(x[4]) | ((u32)f2bf(x[5]) << 16);
    o.w = (u32)f2bf(x[6]) | ((u32)f2bf(x[7]) << 16);
    return o;
}

// ---- fp8 e4m3 helpers ------------------------------------------------------
#ifndef HAVE_HW_FP8
__device__ __forceinline__ float fp8_dec1(u32 b) {
    u32 s = b >> 7, em = b & 0x7F;
    float mag;
    if (em < 8) mag = (float)em * 0.001953125f;                      // subnormal, 2^-9
    else {
        u32 bits = (((em >> 3) + 120u) << 23) | ((em & 7u) << 20);
        mag = __uint_as_float(bits);
    }
    return s ? -mag : mag;
}
__device__ __forceinline__ u32 fp8_enc1(float f) {
    float a = fabsf(f);
    u32 s = (__float_as_uint(f) >> 31) << 7;
    if (a < 0.015625f) {
        int n = (int)rintf(a * 512.0f);                              // 0..8
        return s | (u32)n;
    }
    u32 u = __float_as_uint(a);
    u32 r = u + 0x0007FFFFu + ((u >> 20) & 1u);                      // RNE at bit 20
    int ee = (int)((r >> 23) & 0xFF) - 127 + 7;
    if (ee >= 16) return s | 0x7Eu;                                  // clamp to 448
    return s | ((u32)ee << 3) | ((r >> 20) & 7u);
}
#endif

__device__ __forceinline__ void unpack8_fp8(uint2 rv, float* x) {
#ifdef HAVE_HW_FP8
    typedef float floatx2 __attribute__((ext_vector_type(2)));
    floatx2 a0 = __builtin_amdgcn_cvt_pk_f32_fp8(rv.x, false);
    floatx2 a1 = __builtin_amdgcn_cvt_pk_f32_fp8(rv.x, true);
    floatx2 a2 = __builtin_amdgcn_cvt_pk_f32_fp8(rv.y, false);
    floatx2 a3 = __builtin_amdgcn_cvt_pk_f32_fp8(rv.y, true);
    x[0] = a0.x; x[1] = a0.y; x[2] = a1.x; x[3] = a1.y;
    x[4] = a2.x; x[5] = a2.y; x[6] = a3.x; x[7] = a3.y;
#else
    x[0] = fp8_dec1(rv.x & 0xFF);         x[1] = fp8_dec1((rv.x >> 8) & 0xFF);
    x[2] = fp8_dec1((rv.x >> 16) & 0xFF); x[3] = fp8_dec1(rv.x >> 24);
    x[4] = fp8_dec1(rv.y & 0xFF);         x[5] = fp8_dec1((rv.y >> 8) & 0xFF);
    x[6] = fp8_dec1((rv.y >> 16) & 0xFF); x[7] = fp8_dec1(rv.y >> 24);
#endif
}
__device__ __forceinline__ uint2 pack8_fp8(const float* x) {
    uint2 o;
#ifdef HAVE_HW_FP8
    int v0 = 0, v1 = 0;
    v0 = __builtin_amdgcn_cvt_pk_fp8_f32(x[0], x[1], v0, false);
    v0 = __builtin_amdgcn_cvt_pk_fp8_f32(x[2], x[3], v0, true);
    v1 = __builtin_amdgcn_cvt_pk_fp8_f32(x[4], x[5], v1, false);
    v1 = __builtin_amdgcn_cvt_pk_fp8_f32(x[6], x[7], v1, true);
    o.x = (u32)v0; o.y = (u32)v1;
#else
    o.x = fp8_enc1(x[0]) | (fp8_enc1(x[1]) << 8) | (fp8_enc1(x[2]) << 16) | (fp8_enc1(x[3]) << 24);
    o.y = fp8_enc1(x[4]) | (fp8_enc1(x[5]) << 8) | (fp8_enc1(x[6]) << 16) | (fp8_enc1(x[7]) << 24);
#endif
    return o;
}

__device__ __forceinline__ void fma_rowW(float* acc, uint2 rv, int rel,
                                         const float* __restrict__ weight, int seg) {
    float x[8]; unpack8_fp8(rv, x);
    const float4* wp = (const float4*)(weight + rel * CDIM + seg * 8);
    float4 w0 = wp[0], w1 = wp[1];
    acc[0] += x[0] * w0.x; acc[1] += x[1] * w0.y;
    acc[2] += x[2] * w0.z; acc[3] += x[3] * w0.w;
    acc[4] += x[4] * w1.x; acc[5] += x[5] * w1.y;
    acc[6] += x[6] * w1.z; acc[7] += x[7] * w1.w;
}
__device__ __forceinline__ void fma_rowV(float* acc, uint2 rv, float v) {
    float x[8]; unpack8_fp8(rv, x);
    #pragma unroll
    for (int k = 0; k < 8; ++k) acc[k] += v * x[k];
}

// in-LDS exclusive scan of a 256-entry histogram; sbase[t] = excl
__device__ __forceinline__ void lds_scan256(const int* __restrict__ hist, int* sbase,
                                            int* stmp) {
    int t = threadIdx.x;
    int v = hist[t];
    stmp[t] = v; __syncthreads();
    #pragma unroll
    for (int d = 1; d < 256; d <<= 1) {
        int x = (t >= d) ? stmp[t - d] : 0;
        __syncthreads();
        stmp[t] += x;
        __syncthreads();
    }
    sbase[t] = stmp[t] - v;
    __syncthreads();
}

// ============ kernel A: cvt(f32->fp8) + 2x coarse hist + disen/cor ===========
__device__ void dev_cvt(int b, const float* __restrict__ in, u8* __restrict__ out) {
    int i = b * 256 + threadIdx.x;
    const float4* p = (const float4*)(in + (size_t)i * 8);
    float4 a = p[0], bb = p[1];
    float x[8] = {a.x, a.y, a.z, a.w, bb.x, bb.y, bb.z, bb.w};
    *(uint2*)(out + (size_t)i * 8) = pack8_fp8(x);
}

__device__ void dev_coarse_hist(int b, const int* __restrict__ idx, int n,
                                int* __restrict__ bhist) {
    __shared__ int lh[256];
    int t = threadIdx.x;
    lh[t] = 0; __syncthreads();
    int base = b * ACHUNK;
    #pragma unroll
    for (int k = 0; k < 16; ++k) {
        int i = base + k * 256 + t;
        if (i < n) atomicAdd(&lh[idx[i] >> 10], 1);
    }
    __syncthreads();
    if (lh[t]) atomicAdd(&bhist[t], lh[t]);
}

__device__ void dev_disen_cor(const float* __restrict__ att,
                              const float* __restrict__ weight,
                              float* __restrict__ dw, float* __restrict__ cor_out) {
    int tid = threadIdx.x;
    int f = tid >> 6, c = tid & 63;
    float m = -1e30f;
    for (int r = 0; r < N_REL; ++r) m = fmaxf(m, att[f * N_REL + r]);
    float e[N_REL], s = 0.0f;
    for (int r = 0; r < N_REL; ++r) { e[r] = __expf(att[f * N_REL + r] - m); s += e[r]; }
    float acc = 0.0f;
    for (int r = 0; r < N_REL; ++r) acc += (e[r] / s) * weight[r * CDIM + c];
    dw[f * CDIM + c] = acc;

    if (tid == 0) {
        float rowsum[N_FACTORS];
        for (int ff = 0; ff < N_FACTORS; ++ff) {
            float ss = 0.0f;
            for (int j = 0; j < N_REL; ++j) ss += att[ff * N_REL + j];
            rowsum[ff] = ss;
        }
        float cor = 0.0f;
        for (int i = 0; i < N_REL; ++i) {
            float nsq = 0.0f, ttl = 0.0f;
            for (int ff = 0; ff < N_FACTORS; ++ff) {
                float a = att[ff * N_REL + i];
                nsq += a * a;
                ttl += a * rowsum[ff];
            }
            float n = sqrtf(nsq);
            float pos = 0.0f;
            for (int ff = 0; ff < N_FACTORS; ++ff) {
                float a = att[ff * N_REL + i] / n;
                pos += a * a;
            }
            cor += (ttl - pos) / TEMP;
        }
        *cor_out = cor;
    }
}

__global__ __launch_bounds__(256) void prep_kernel(const float* __restrict__ entity_emb,
                                                   u8* __restrict__ ef8,
                                                   const int* __restrict__ head,
                                                   const int* __restrict__ inter_rows,
                                                   int* __restrict__ bhe,
                                                   int* __restrict__ bhu,
                                                   const float* __restrict__ att,
                                                   const float* __restrict__ weight,
                                                   float* __restrict__ dw,
                                                   float* __restrict__ cor_out) {
    int bid = blockIdx.x;
    if (bid < GCVT)                 dev_cvt(bid, entity_emb, ef8);
    else if (bid < GCVT + GA)       dev_coarse_hist(bid - GCVT, head, N_EDGES, bhe);
    else if (bid < GCVT + 2 * GA)   dev_coarse_hist(bid - GCVT - GA, inter_rows, NNZ, bhu);
    else                            dev_disen_cor(att, weight, dw, cor_out);
}

// ============ kernel B: bin passes (in-block scan of bhist + zcur reserve) ===
__device__ void dev_bin_edges(int b, const int* __restrict__ head,
                              const int* __restrict__ tail, const int* __restrict__ etype,
                              const int* __restrict__ bhist,
                              int* __restrict__ zcur, int* __restrict__ binbuf) {
    __shared__ int sbase[256], stmp[256];
    __shared__ int lh[256], lbase[256];
    int t = threadIdx.x;
    lds_scan256(bhist, sbase, stmp);
    lh[t] = 0; __syncthreads();
    int base = b * ACHUNK;
    int rec[16], rnk[16], bkt[16];
    #pragma unroll
    for (int k = 0; k < 16; ++k) {
        int i = base + k * 256 + t;
        rnk[k] = -1; rec[k] = 0; bkt[k] = 0;
        if (i < N_EDGES) {
            int h = head[i];
            bkt[k] = h >> 10;
            rec[k] = ((h & 1023) << 22) | ((etype[i] - 1) << 18) | tail[i];
            rnk[k] = atomicAdd(&lh[bkt[k]], 1);
        }
    }
    __syncthreads();
    lbase[t] = lh[t] ? (sbase[t] + atomicAdd(&zcur[t], lh[t])) : 0;
    __syncthreads();
    #pragma unroll
    for (int k = 0; k < 16; ++k)
        if (rnk[k] >= 0) binbuf[lbase[bkt[k]] + rnk[k]] = rec[k];
}

__device__ void dev_bin_inter(int b, const int* __restrict__ rows,
                              const int* __restrict__ cols, const float* __restrict__ vals,
                              const int* __restrict__ bhist,
                              int* __restrict__ zcur, int2* __restrict__ binbuf) {
    __shared__ int sbase[256], stmp[256];
    __shared__ int lh[256], lbase[256];
    int t = threadIdx.x;
    lds_scan256(bhist, sbase, stmp);
    lh[t] = 0; __syncthreads();
    int base = b * ACHUNK;
    int recx[16], recy[16], rnk[16], bkt[16];
    #pragma unroll
    for (int k = 0; k < 16; ++k) {
        int i = base + k * 256 + t;
        rnk[k] = -1; recx[k] = 0; recy[k] = 0; bkt[k] = 0;
        if (i < NNZ) {
            int r = rows[i];
            bkt[k] = r >> 10;
            recx[k] = ((r & 1023) << 18) | cols[i];
            recy[k] = __float_as_int(vals[i]);
            rnk[k] = atomicAdd(&lh[bkt[k]], 1);
        }
    }
    __syncthreads();
    lbase[t] = lh[t] ? (sbase[t] + atomicAdd(&zcur[t], lh[t])) : 0;
    __syncthreads();
    #pragma unroll
    for (int k = 0; k < 16; ++k)
        if (rnk[k] >= 0) {
            int2 p; p.x = recx[k]; p.y = recy[k];
            binbuf[lbase[bkt[k]] + rnk[k]] = p;
        }
}

__global__ __launch_bounds__(256) void bin_kernel(const int* __restrict__ head,
                                                  const int* __restrict__ tail,
                                                  const int* __restrict__ etype,
                                                  const int* __restrict__ rows,
                                                  const int* __restrict__ cols,
                                                  const float* __restrict__ vals,
                                                  const int* __restrict__ bhe,
                                                  const int* __restrict__ bhu,
                                                  int* __restrict__ zce, int* __restrict__ zcu,
                                                  int* __restrict__ bine, int2* __restrict__ binu) {
    int bid = blockIdx.x;
    if (bid < GA) dev_bin_edges(bid, head, tail, etype, bhe, zce, bine);
    else          dev_bin_inter(bid - GA, rows, cols, vals, bhu, zcu, binu);
}

// ============ kernel C: per-bucket CSR finalize + degree histogram ===========
__device__ void dev_build_e(int b, const int* __restrict__ bhist,
                            const int* __restrict__ binbuf,
                            int* __restrict__ eoff, int* __restrict__ epk,
                            int* __restrict__ dbinE) {
    __shared__ int sbase[256], stmp[256];
    __shared__ int lh[CB];
    __shared__ int ss[256];
    __shared__ int ldeg[64];
    int t = threadIdx.x;
    lds_scan256(bhist, sbase, stmp);
    int bstart = sbase[b], bend = sbase[b] + bhist[b];
    #pragma unroll
    for (int k = 0; k < 4; ++k) lh[t * 4 + k] = 0;
    if (t < 64) ldeg[t] = 0;
    __syncthreads();
    for (int j = bstart + t; j < bend; j += 256)
        atomicAdd(&lh[(u32)binbuf[j] >> 22], 1);
    __syncthreads();
    int v[4], acc = 0;
    #pragma unroll
    for (int k = 0; k < 4; ++k) { v[k] = lh[t * 4 + k]; acc += v[k]; }
    ss[t] = acc; __syncthreads();
    #pragma unroll
    for (int d = 1; d < 256; d <<= 1) {
        int x = (t >= d) ? ss[t - d] : 0;
        __syncthreads();
        ss[t] += x;
        __syncthreads();
    }
    int excl = ss[t] - acc;
    int hbase = b * CB;
    #pragma unroll
    for (int k = 0; k < 4; ++k) {
        int hl = t * 4 + k;
        int h = hbase + hl;
        if (h < N_ENTITIES) {
            eoff[h] = bstart + excl;
            atomicAdd(&ldeg[63 - min(v[k], 63)], 1);   // descending-degree bins
        }
        lh[hl] = excl;
        excl += v[k];
    }
    __syncthreads();
    if (t < 64 && ldeg[t]) atomicAdd(&dbinE[t], ldeg[t]);
    if (b == 0 && t == 0) eoff[N_ENTITIES] = N_EDGES;
    for (int j = bstart + t; j < bend; j += 256) {
        int rec = binbuf[j];
        int pos = atomicAdd(&lh[(u32)rec >> 22], 1);
        epk[bstart + pos] = rec & 0x3FFFFF;   // rel<<18 | tail
    }
}

__device__ void dev_build_u(int b, const int* __restrict__ bhist,
                            const int2* __restrict__ binbuf,
                            int* __restrict__ uoff, int2* __restrict__ ucv,
                            int* __restrict__ dbinU) {
    __shared__ int sbase[256], stmp[256];
    __shared__ int lh[CB];
    __shared__ int ss[256];
    __shared__ int ldeg[64];
    int t = threadIdx.x;
    lds_scan256(bhist, sbase, stmp);
    int bstart = sbase[b], bend = sbase[b] + bhist[b];
    #pragma unroll
    for (int k = 0; k < 4; ++k) lh[t * 4 + k] = 0;
    if (t < 64) ldeg[t] = 0;
    __syncthreads();
    for (int j = bstart + t; j < bend; j += 256)
        atomicAdd(&lh[(u32)binbuf[j].x >> 18], 1);
    __syncthreads();
    int v[4], acc = 0;
    #pragma unroll
    for (int k = 0; k < 4; ++k) { v[k] = lh[t * 4 + k]; acc += v[k]; }
    ss[t] = acc; __syncthreads();
    #pragma unroll
    for (int d = 1; d < 256; d <<= 1) {
        int x = (t >= d) ? ss[t - d] : 0;
        __syncthreads();
        ss[t] += x;
        __syncthreads();
    }
    int excl = ss[t] - acc;
    int ubase = b * CB;
    #pragma unroll
    for (int k = 0; k < 4; ++k) {
        int ul = t * 4 + k;
        int u = ubase + ul;
        if (u < N_USERS) {
            uoff[u] = bstart + excl;
            atomicAdd(&ldeg[63 - min(v[k], 63)], 1);
        }
        lh[ul] = excl;
        excl += v[k];
    }
    __syncthreads();
    if (t < 64 && ldeg[t]) atomicAdd(&dbinU[t], ldeg[t]);
    if (b == 0 && t == 0) uoff[N_USERS] = NNZ;
    for (int j = bstart + t; j < bend; j += 256) {
        int2 rec = binbuf[j];
        int pos = atomicAdd(&lh[(u32)rec.x >> 18], 1);
        int2 out; out.x = rec.x & 0x3FFFF; out.y = rec.y;
        ucv[bstart + pos] = out;
    }
}

__global__ __launch_bounds__(256) void build_kernel(const int* __restrict__ bhe,
                                                    const int* __restrict__ bhu,
                                                    const int* __restrict__ bine,
                                                    const int2* __restrict__ binu,
                                                    int* __restrict__ eoff, int* __restrict__ epk,
                                                    int* __restrict__ uoff, int2* __restrict__ ucv,
                                                    int* __restrict__ dbinE, int* __restrict__ dbinU) {
    int bid = blockIdx.x;
    if (bid < NBE) dev_build_e(bid, bhe, bine, eoff, epk, dbinE);
    else           dev_build_u(bid - NBE, bhu, binu, uoff, ucv, dbinU);
}

// ============ kernel D: degree-sorted permutation (in-block deg scan) ========
__device__ void dev_perm(int b, int n, const int* __restrict__ off,
                         const int* __restrict__ dbin,
                         int* __restrict__ zdeg, int2* __restrict__ perm) {
    __shared__ int dbase[64], dtmp[64];
    __shared__ int lh[64], lbase[64];
    int t = threadIdx.x;
    if (t < 64) { dtmp[t] = dbin[t]; lh[t] = 0; }
    __syncthreads();
    if (t < 64) {
        int v = dtmp[t];
        #pragma unroll
        for (int d = 1; d < 64; d <<= 1) {
            int x = (t >= d) ? dtmp[t - d] : 0;
            __syncthreads();
            dtmp[t] += x;
            __syncthreads();
        }
        dbase[t] = dtmp[t] - v;
    } else {
        #pragma unroll
        for (int d = 1; d < 64; d <<= 1) { __syncthreads(); __syncthreads(); }
    }
    __syncthreads();
    int base = b * PCHUNK;
    int rnk[16], bin[16], deg[16], st[16];
    #pragma unroll
    for (int k = 0; k < 16; ++k) {
        int i = base + k * 256 + t;
        rnk[k] = -1;
        if (i < n) {
            int s0 = off[i], s1 = off[i + 1];
            deg[k] = s1 - s0; st[k] = s0;
            bin[k] = 63 - min(deg[k], 63);     // descending degree
            rnk[k] = atomicAdd(&lh[bin[k]], 1);
        }
    }
    __syncthreads();
    if (t < 64) lbase[t] = lh[t] ? (dbase[t] + atomicAdd(&zdeg[t], lh[t])) : 0;
    __syncthreads();
    #pragma unroll
    for (int k = 0; k < 16; ++k)
        if (rnk[k] >= 0) {
            int i = base + k * 256 + t;
            int2 p;
            p.x = (int)(((u32)min(deg[k], 16383) << 18) | (u32)i);
            p.y = st[k];
            perm[lbase[bin[k]] + rnk[k]] = p;
        }
}

__global__ __launch_bounds__(256) void perm_kernel(const int* __restrict__ eoff,
                                                   const int* __restrict__ uoff,
                                                   const int* __restrict__ dbinE,
                                                   const int* __restrict__ dbinU,
                                                   int* __restrict__ zdegE, int* __restrict__ zdegU,
                                                   int2* __restrict__ permE, int2* __restrict__ permU) {
    int bid = blockIdx.x;
    if (bid < GPE) dev_perm(bid, N_ENTITIES, eoff, dbinE, zdegE, permE);
    else           dev_perm(bid - GPE, N_USERS, uoff, dbinU, zdegU, permU);
}

// ============ hop kernels (kg + user), 4-deep pipelined gather ===============
__device__ void dev_kg_hop(int widg, const u8* __restrict__ esrc,
                           const int2* __restrict__ permE,
                           const int* __restrict__ epk,
                           const float* __restrict__ weight,
                           const float* __restrict__ emb0,
                           u8* __restrict__ enew, float* __restrict__ eres, int last) {
    int lane = threadIdx.x & 63;
    int slot = lane >> 3, seg = lane & 7;
    int2 pe = permE[widg * 8 + slot];
    u32 px = (u32)pe.x;
    int d = px >> 18, h = (int)(px & 0x3FFFFu), s = pe.y;
    int dmax = d;
    dmax = max(dmax, __shfl_xor(dmax, 8, 64));
    dmax = max(dmax, __shfl_xor(dmax, 16, 64));
    dmax = max(dmax, __shfl_xor(dmax, 32, 64));

    float acc[8];
    #pragma unroll
    for (int k = 0; k < 8; ++k) acc[k] = 0.0f;
    const uint2 uz = make_uint2(0u, 0u);

    for (int it = 0; it < dmax; it += 4) {
        int pk[4]; uint2 rv[4];
        #pragma unroll
        for (int q = 0; q < 4; ++q)
            pk[q] = (it + q < d) ? epk[s + it + q] : 0;
        #pragma unroll
        for (int q = 0; q < 4; ++q)
            rv[q] = (it + q < d)
                  ? *(const uint2*)(esrc + (size_t)(pk[q] & 0x3FFFF) * CDIM + seg * 8) : uz;
        #pragma unroll
        for (int q = 0; q < 4; ++q)
            fma_rowW(acc, rv[q], pk[q] >> 18, weight, seg);
    }
    float inv = 1.0f / fmaxf((float)d, 1.0f);
    float ssq = 0.0f;
    #pragma unroll
    for (int k = 0; k < 8; ++k) { acc[k] *= inv; ssq += acc[k] * acc[k]; }
    ssq += __shfl_xor(ssq, 1, 64);
    ssq += __shfl_xor(ssq, 2, 64);
    ssq += __shfl_xor(ssq, 4, 64);
    float rn = 1.0f / fmaxf(sqrtf(ssq), 1e-12f);
    #pragma unroll
    for (int k = 0; k < 8; ++k) acc[k] *= rn;

    size_t base = (size_t)h * CDIM + seg * 8;
    if (!last) {
        *(uint2*)(enew + base) = pack8_fp8(acc);
    } else {
        uint2 pv = *(const uint2*)(esrc + base);   // esrc == hop0 output eA (fp8)
        float o0[8]; unpack8_fp8(pv, o0);
        float4 a = *(const float4*)(emb0 + base);
        float4 b = *(const float4*)(emb0 + base + 4);
        float4 r0, r1;
        r0.x = a.x + o0[0] + acc[0]; r0.y = a.y + o0[1] + acc[1];
        r0.z = a.z + o0[2] + acc[2]; r0.w = a.w + o0[3] + acc[3];
        r1.x = b.x + o0[4] + acc[4]; r1.y = b.y + o0[5] + acc[5];
        r1.z = b.z + o0[6] + acc[6]; r1.w = b.w + o0[7] + acc[7];
        *(float4*)(eres + base) = r0;
        *(float4*)(eres + base + 4) = r1;
    }
}

__device__ void dev_user_hop(int widg, const float* __restrict__ uoldf,
                             const u16* __restrict__ uoldb,
                             const u8* __restrict__ esrc,
                             const int2* __restrict__ permU,
                             const int2* __restrict__ ucv,
                             const float* __restrict__ latent,
                             const float* __restrict__ dw,
                             const float* __restrict__ uemb0,
                             u16* __restrict__ unew, float* __restrict__ ures, int last) {
    int lane = threadIdx.x & 63;
    int slot = lane >> 3, seg = lane & 7;
    int2 pe = permU[widg * 8 + slot];
    u32 px = (u32)pe.x;
    int d = px >> 18, u = (int)(px & 0x3FFFFu), s = pe.y;
    int dmax = d;
    dmax = max(dmax, __shfl_xor(dmax, 8, 64));
    dmax = max(dmax, __shfl_xor(dmax, 16, 64));
    dmax = max(dmax, __shfl_xor(dmax, 32, 64));

    float acc[8];
    #pragma unroll
    for (int k = 0; k < 8; ++k) acc[k] = 0.0f;
    const uint2 uz = make_uint2(0u, 0u);
    const int2 cz = make_int2(0, 0);

    for (int it = 0; it < dmax; it += 4) {
        int2 cc[4]; uint2 rv[4];
        #pragma unroll
        for (int q = 0; q < 4; ++q)
            cc[q] = (it + q < d) ? ucv[s + it + q] : cz;
        #pragma unroll
        for (int q = 0; q < 4; ++q)
            rv[q] = (it + q < d)
                  ? *(const uint2*)(esrc + (size_t)cc[q].x * CDIM + seg * 8) : uz;
        #pragma unroll
        for (int q = 0; q < 4; ++q)
            fma_rowV(acc, rv[q], __int_as_float(cc[q].y));
    }

    float uo[8];
    size_t ubase = (size_t)u * CDIM + seg * 8;
    if (uoldb) {
        uint4 pv = *(const uint4*)(uoldb + ubase);
        unpack8_bf(pv, uo);
    } else {
        float4 a = *(const float4*)(uoldf + ubase);
        float4 b = *(const float4*)(uoldf + ubase + 4);
        uo[0] = a.x; uo[1] = a.y; uo[2] = a.z; uo[3] = a.w;
        uo[4] = b.x; uo[5] = b.y; uo[6] = b.z; uo[7] = b.w;
    }
    float dts[N_FACTORS];
    #pragma unroll
    for (int f = 0; f < N_FACTORS; ++f) {
        const float4* lp = (const float4*)(latent + f * CDIM + seg * 8);
        float4 l0 = lp[0], l1 = lp[1];
        float p = uo[0] * l0.x + uo[1] * l0.y + uo[2] * l0.z + uo[3] * l0.w +
                  uo[4] * l1.x + uo[5] * l1.y + uo[6] * l1.z + uo[7] * l1.w;
        p += __shfl_xor(p, 1, 64);
        p += __shfl_xor(p, 2, 64);
        p += __shfl_xor(p, 4, 64);
        dts[f] = p;
    }
    float m = fmaxf(fmaxf(dts[0], dts[1]), fmaxf(dts[2], dts[3]));
    float e0 = __expf(dts[0] - m), e1 = __expf(dts[1] - m);
    float e2 = __expf(dts[2] - m), e3 = __expf(dts[3] - m);
    float inv_ssum = 1.0f / (e0 + e1 + e2 + e3);
    e0 *= inv_ssum; e1 *= inv_ssum; e2 *= inv_ssum; e3 *= inv_ssum;

    const float4* d0p = (const float4*)(dw + 0 * CDIM + seg * 8);
    const float4* d1p = (const float4*)(dw + 1 * CDIM + seg * 8);
    const float4* d2p = (const float4*)(dw + 2 * CDIM + seg * 8);
    const float4* d3p = (const float4*)(dw + 3 * CDIM + seg * 8);
    float4 ga0 = d0p[0], ga1 = d0p[1];
    float4 gb0 = d1p[0], gb1 = d1p[1];
    float4 gc0 = d2p[0], gc1 = d2p[1];
    float4 gd0 = d3p[0], gd1 = d3p[1];
    float g[8];
    g[0] = e0 * ga0.x + e1 * gb0.x + e2 * gc0.x + e3 * gd0.x;
    g[1] = e0 * ga0.y + e1 * gb0.y + e2 * gc0.y + e3 * gd0.y;
    g[2] = e0 * ga0.z + e1 * gb0.z + e2 * gc0.z + e3 * gd0.z;
    g[3] = e0 * ga0.w + e1 * gb0.w + e2 * gc0.w + e3 * gd0.w;
    g[4] = e0 * ga1.x + e1 * gb1.x + e2 * gc1.x + e3 * gd1.x;
    g[5] = e0 * ga1.y + e1 * gb1.y + e2 * gc1.y + e3 * gd1.y;
    g[6] = e0 * ga1.z + e1 * gb1.z + e2 * gc1.z + e3 * gd1.z;
    g[7] = e0 * ga1.w + e1 * gb1.w + e2 * gc1.w + e3 * gd1.w;

    float ssq = 0.0f;
    #pragma unroll
    for (int k = 0; k < 8; ++k) {
        acc[k] = acc[k] * (1.0f + g[k]);
        ssq += acc[k] * acc[k];
    }
    ssq += __shfl_xor(ssq, 1, 64);
    ssq += __shfl_xor(ssq, 2, 64);
    ssq += __shfl_xor(ssq, 4, 64);
    float rn = 1.0f / fmaxf(sqrtf(ssq), 1e-12f);
    #pragma unroll
    for (int k = 0; k < 8; ++k) acc[k] *= rn;

    if (!last) {
        *(uint4*)(unew + ubase) = pack8_bf(acc);
    } else {
        float4 a = *(const float4*)(uemb0 + ubase);
        float4 b = *(const float4*)(uemb0 + ubase + 4);
        float4 r0, r1;
        r0.x = a.x + uo[0] + acc[0]; r0.y = a.y + uo[1] + acc[1];
        r0.z = a.z + uo[2] + acc[2]; r0.w = a.w + uo[3] + acc[3];
        r1.x = b.x + uo[4] + acc[4]; r1.y = b.y + uo[5] + acc[5];
        r1.z = b.z + uo[6] + acc[6]; r1.w = b.w + uo[7] + acc[7];
        *(float4*)(ures + ubase) = r0;
        *(float4*)(ures + ubase + 4) = r1;
    }
}

__global__ __launch_bounds__(256) void hop_kernel(const u8* __restrict__ e_src,
                                                  const int2* __restrict__ permE,
                                                  const int* __restrict__ epk,
                                                  const float* __restrict__ weight,
                                                  const float* __restrict__ entity_emb,
                                                  u8* __restrict__ eA,
                                                  float* __restrict__ eres,
                                                  const float* __restrict__ uoldf,
                                                  const u16* __restrict__ uoldb,
                                                  const int2* __restrict__ permU,
                                                  const int2* __restrict__ ucv,
                                                  const float* __restrict__ latent,
                                                  const float* __restrict__ dw,
                                                  const float* __restrict__ user_emb,
                                                  u16* __restrict__ uA,
                                                  float* __restrict__ ures,
                                                  int last) {
    int bid = blockIdx.x;
    int wave = threadIdx.x >> 6;
    if (bid < KG_BLOCKS) {
        dev_kg_hop(bid * 4 + wave, e_src, permE, epk, weight, entity_emb, eA, eres, last);
    } else {
        dev_user_hop((bid - KG_BLOCKS) * 4 + wave, uoldf, uoldb, e_src, permU, ucv,
                     latent, dw, user_emb, uA, ures, last);
    }
}

static inline size_t align16(size_t x) { return (x + 15) & ~(size_t)15; }

extern "C" void kernel_launch(void* const* d_in, const int* in_sizes, int n_in,
                              void* d_out, int out_size, void* d_ws, size_t ws_size,
                              hipStream_t stream) {
    const float* user_emb   = (const float*)d_in[0];
    const float* entity_emb = (const float*)d_in[1];
    const float* latent_emb = (const float*)d_in[2];
    const float* weight     = (const float*)d_in[3];
    const float* att        = (const float*)d_in[4];
    const int*   edge_index = (const int*)d_in[5];
    const int*   edge_type  = (const int*)d_in[6];
    const int*   inter_rows = (const int*)d_in[7];
    const int*   inter_cols = (const int*)d_in[8];
    const float* inter_vals = (const float*)d_in[9];

    float* eres = (float*)d_out;
    float* ures = eres + (size_t)N_ENTITIES * CDIM;
    float* cor  = ures + (size_t)N_USERS * CDIM;

    char* ws = (char*)d_ws;
    u8*    ef8   = (u8*)ws;   ws += align16(sizeof(u8) * (size_t)N_ENTITIES * CDIM);
    u8*    eA    = (u8*)ws;   ws += align16(sizeof(u8) * (size_t)N_ENTITIES * CDIM);
    u16*   uA    = (u16*)ws;  ws += align16(sizeof(u16) * (size_t)N_USERS * CDIM);
    int*   eoff  = (int*)ws;  ws += align16(sizeof(int) * (N_ENTITIES + 1));
    int*   epk   = (int*)ws;  ws += align16(sizeof(int) * N_EDGES);
    int*   uoff  = (int*)ws;  ws += align16(sizeof(int) * (N_USERS + 1));
    int2*  ucv   = (int2*)ws; ws += align16(sizeof(int2) * NNZ);
    int*   bine  = (int*)ws;  ws += align16(sizeof(int) * N_EDGES);
    int2*  binu  = (int2*)ws; ws += align16(sizeof(int2) * NNZ);
    int*   ctrs  = (int*)ws;  ws += align16(sizeof(int) * 1280);
    int2*  permE = (int2*)ws; ws += align16(sizeof(int2) * N_ENTITIES);
    int2*  permU = (int2*)ws; ws += align16(sizeof(int2) * N_USERS);
    float* dw    = (float*)ws; ws += align16(sizeof(float) * N_FACTORS * CDIM);

    // counter layout (single 5 KB memset zeroes everything)
    int* bhe   = ctrs;          // 256
    int* bhu   = ctrs + 256;    // 256
    int* dbinE = ctrs + 512;    // 64
    int* dbinU = ctrs + 576;    // 64
    int* zce   = ctrs + 640;    // 256
    int* zcu   = ctrs + 896;    // 256
    int* zdegE = ctrs + 1152;   // 64
    int* zdegU = ctrs + 1216;   // 64

    const int* head = edge_index;
    const int* tail = edge_index + N_EDGES;

    (void)hipMemsetAsync(ctrs, 0, sizeof(int) * 1280, stream);

    prep_kernel<<<GCVT + 2 * GA + 1, 256, 0, stream>>>(entity_emb, ef8, head, inter_rows,
                                                       bhe, bhu, att, weight, dw, cor);
    bin_kernel<<<2 * GA, 256, 0, stream>>>(head, tail, edge_type,
                                           inter_rows, inter_cols, inter_vals,
                                           bhe, bhu, zce, zcu, bine, binu);
    build_kernel<<<NBE + NBU, 256, 0, stream>>>(bhe, bhu, bine, binu,
                                                eoff, epk, uoff, ucv, dbinE, dbinU);
    perm_kernel<<<GPE + GPU_, 256, 0, stream>>>(eoff, uoff, dbinE, dbinU,
                                                zdegE, zdegU, permE, permU);

    // hop 0: gather from ef8; write fp8 eA + bf16 uA
    hop_kernel<<<KG_BLOCKS + USER_BLOCKS, 256, 0, stream>>>(
        ef8, permE, epk, weight, entity_emb, eA, eres,
        user_emb, (const u16*)nullptr, permU, ucv, latent_emb, dw, user_emb, uA, ures, 0);
    // hop 1: gather from eA; write res = emb0 + o0 + o1
    hop_kernel<<<KG_BLOCKS + USER_BLOCKS, 256, 0, stream>>>(
        eA, permE, epk, weight, entity_emb, (u8*)nullptr, eres,
        (const float*)nullptr, uA, permU, ucv, latent_emb, dw, user_emb, (u16*)nullptr, ures, 1);
}

// Round 13
// 203.916 us; speedup vs baseline: 1.0935x; 1.0784x over previous
//
#include <hip/hip_runtime.h>
#include <math.h>

#define N_USERS    100000
#define N_ENTITIES 200000
#define N_EDGES    1000000
#define NNZ        1000000
#define CDIM       64
#define N_FACTORS  4
#define N_REL      10
#define TEMP       0.2f

#define CB         1024
#define NBE        196      // ceil(200000/1024)
#define NBU        98       // ceil(100000/1024)
#define CAPE       8192     // padded edges per entity bucket (mean 5102, +43 sigma)
#define CAPU       12288    // padded nnz per user bucket   (mean 10204, +20 sigma)
#define ACHUNK     4096
#define GA         245      // ceil(1e6/4096)
#define GCVT       6250     // (200000*64/8)/256
#define KG_BLOCKS  6250     // 200000 / 32 rows per block
#define USER_BLOCKS 3125    // 100000 / 32
#define PCHUNK     4096
#define GPE        49       // ceil(200000/4096)
#define GPU_       25       // ceil(100000/4096)

typedef unsigned int u32;
typedef unsigned short u16;
typedef unsigned char u8;

#if defined(__has_builtin)
#if __has_builtin(__builtin_amdgcn_cvt_pk_f32_fp8) && __has_builtin(__builtin_amdgcn_cvt_pk_fp8_f32)
#define HAVE_HW_FP8 1
#endif
#endif

// ---- bf16 helpers ----------------------------------------------------------
__device__ __forceinline__ float bflo(u32 w) { return __uint_as_float(w << 16); }
__device__ __forceinline__ float bfhi(u32 w) { return __uint_as_float(w & 0xFFFF0000u); }
__device__ __forceinline__ u16 f2bf(float f) {
    u32 u = __float_as_uint(f);
    u32 r = u + 0x7FFFu + ((u >> 16) & 1u);   // RNE
    return (u16)(r >> 16);
}
__device__ __forceinline__ void unpack8_bf(uint4 rv, float* x) {
    x[0] = bflo(rv.x); x[1] = bfhi(rv.x);
    x[2] = bflo(rv.y); x[3] = bfhi(rv.y);
    x[4] = bflo(rv.z); x[5] = bfhi(rv.z);
    x[6] = bflo(rv.w); x[7] = bfhi(rv.w);
}
__device__ __forceinline__ uint4 pack8_bf(const float* x) {
    uint4 o;
    o.x = (u32)f2bf(x[0]) | ((u32)f2bf(x[1]) << 16);
    o.y = (u32)f2bf(x[2]) | ((u32)f2bf(x[3]) << 16);
    o.z = (u32)f2bf(x[4]) | ((u32)f2bf(x[5]) << 16);
    o.w = (u32)f2bf(x[6]) | ((u32)f2bf(x[7]) << 16);
    return o;
}

// ---- fp8 e4m3 helpers ------------------------------------------------------
#ifndef HAVE_HW_FP8
__device__ __forceinline__ float fp8_dec1(u32 b) {
    u32 s = b >> 7, em = b & 0x7F;
    float mag;
    if (em < 8) mag = (float)em * 0.001953125f;                      // subnormal, 2^-9
    else {
        u32 bits = (((em >> 3) + 120u) << 23) | ((em & 7u) << 20);
        mag = __uint_as_float(bits);
    }
    return s ? -mag : mag;
}
__device__ __forceinline__ u32 fp8_enc1(float f) {
    float a = fabsf(f);
    u32 s = (__float_as_uint(f) >> 31) << 7;
    if (a < 0.015625f) {
        int n = (int)rintf(a * 512.0f);                              // 0..8
        return s | (u32)n;
    }
    u32 u = __float_as_uint(a);
    u32 r = u + 0x0007FFFFu + ((u >> 20) & 1u);                      // RNE at bit 20
    int ee = (int)((r >> 23) & 0xFF) - 127 + 7;
    if (ee >= 16) return s | 0x7Eu;                                  // clamp to 448
    return s | ((u32)ee << 3) | ((r >> 20) & 7u);
}
#endif

__device__ __forceinline__ void unpack8_fp8(uint2 rv, float* x) {
#ifdef HAVE_HW_FP8
    typedef float floatx2 __attribute__((ext_vector_type(2)));
    floatx2 a0 = __builtin_amdgcn_cvt_pk_f32_fp8(rv.x, false);
    floatx2 a1 = __builtin_amdgcn_cvt_pk_f32_fp8(rv.x, true);
    floatx2 a2 = __builtin_amdgcn_cvt_pk_f32_fp8(rv.y, false);
    floatx2 a3 = __builtin_amdgcn_cvt_pk_f32_fp8(rv.y, true);
    x[0] = a0.x; x[1] = a0.y; x[2] = a1.x; x[3] = a1.y;
    x[4] = a2.x; x[5] = a2.y; x[6] = a3.x; x[7] = a3.y;
#else
    x[0] = fp8_dec1(rv.x & 0xFF);         x[1] = fp8_dec1((rv.x >> 8) & 0xFF);
    x[2] = fp8_dec1((rv.x >> 16) & 0xFF); x[3] = fp8_dec1(rv.x >> 24);
    x[4] = fp8_dec1(rv.y & 0xFF);         x[5] = fp8_dec1((rv.y >> 8) & 0xFF);
    x[6] = fp8_dec1((rv.y >> 16) & 0xFF); x[7] = fp8_dec1(rv.y >> 24);
#endif
}
__device__ __forceinline__ uint2 pack8_fp8(const float* x) {
    uint2 o;
#ifdef HAVE_HW_FP8
    int v0 = 0, v1 = 0;
    v0 = __builtin_amdgcn_cvt_pk_fp8_f32(x[0], x[1], v0, false);
    v0 = __builtin_amdgcn_cvt_pk_fp8_f32(x[2], x[3], v0, true);
    v1 = __builtin_amdgcn_cvt_pk_fp8_f32(x[4], x[5], v1, false);
    v1 = __builtin_amdgcn_cvt_pk_fp8_f32(x[6], x[7], v1, true);
    o.x = (u32)v0; o.y = (u32)v1;
#else
    o.x = fp8_enc1(x[0]) | (fp8_enc1(x[1]) << 8) | (fp8_enc1(x[2]) << 16) | (fp8_enc1(x[3]) << 24);
    o.y = fp8_enc1(x[4]) | (fp8_enc1(x[5]) << 8) | (fp8_enc1(x[6]) << 16) | (fp8_enc1(x[7]) << 24);
#endif
    return o;
}

__device__ __forceinline__ void fma_rowW(float* acc, uint2 rv, int rel,
                                         const float* __restrict__ weight, int seg) {
    float x[8]; unpack8_fp8(rv, x);
    const float4* wp = (const float4*)(weight + rel * CDIM + seg * 8);
    float4 w0 = wp[0], w1 = wp[1];
    acc[0] += x[0] * w0.x; acc[1] += x[1] * w0.y;
    acc[2] += x[2] * w0.z; acc[3] += x[3] * w0.w;
    acc[4] += x[4] * w1.x; acc[5] += x[5] * w1.y;
    acc[6] += x[6] * w1.z; acc[7] += x[7] * w1.w;
}
__device__ __forceinline__ void fma_rowV(float* acc, uint2 rv, float v) {
    float x[8]; unpack8_fp8(rv, x);
    #pragma unroll
    for (int k = 0; k < 8; ++k) acc[k] += v * x[k];
}

// ============ kernel A: cvt(f32->fp8) + direct bin passes + disen/cor ========
__device__ void dev_cvt(int b, const float* __restrict__ in, u8* __restrict__ out) {
    int i = b * 256 + threadIdx.x;
    const float4* p = (const float4*)(in + (size_t)i * 8);
    float4 a = p[0], bb = p[1];
    float x[8] = {a.x, a.y, a.z, a.w, bb.x, bb.y, bb.z, bb.w};
    *(uint2*)(out + (size_t)i * 8) = pack8_fp8(x);
}

// direct bin of edges into padded per-bucket regions (no pre-histogram)
__device__ void dev_bin_edges(int b, const int* __restrict__ head,
                              const int* __restrict__ tail, const int* __restrict__ etype,
                              int* __restrict__ zcur, int* __restrict__ binbuf) {
    __shared__ int lh[256], lbase[256];
    int t = threadIdx.x;
    lh[t] = 0; __syncthreads();
    int base = b * ACHUNK;
    int rec[16], rnk[16], bkt[16];
    #pragma unroll
    for (int k = 0; k < 16; ++k) {
        int i = base + k * 256 + t;
        rnk[k] = -1; rec[k] = 0; bkt[k] = 0;
        if (i < N_EDGES) {
            int h = head[i];
            bkt[k] = h >> 10;
            rec[k] = ((h & 1023) << 22) | ((etype[i] - 1) << 18) | tail[i];
            rnk[k] = atomicAdd(&lh[bkt[k]], 1);
        }
    }
    __syncthreads();
    lbase[t] = lh[t] ? (t * CAPE + atomicAdd(&zcur[t], lh[t])) : 0;
    __syncthreads();
    #pragma unroll
    for (int k = 0; k < 16; ++k)
        if (rnk[k] >= 0) binbuf[lbase[bkt[k]] + rnk[k]] = rec[k];
}

__device__ void dev_bin_inter(int b, const int* __restrict__ rows,
                              const int* __restrict__ cols, const float* __restrict__ vals,
                              int* __restrict__ zcur, int2* __restrict__ binbuf) {
    __shared__ int lh[256], lbase[256];
    int t = threadIdx.x;
    lh[t] = 0; __syncthreads();
    int base = b * ACHUNK;
    int recx[16], recy[16], rnk[16], bkt[16];
    #pragma unroll
    for (int k = 0; k < 16; ++k) {
        int i = base + k * 256 + t;
        rnk[k] = -1; recx[k] = 0; recy[k] = 0; bkt[k] = 0;
        if (i < NNZ) {
            int r = rows[i];
            bkt[k] = r >> 10;
            recx[k] = ((r & 1023) << 18) | cols[i];
            recy[k] = __float_as_int(vals[i]);
            rnk[k] = atomicAdd(&lh[bkt[k]], 1);
        }
    }
    __syncthreads();
    lbase[t] = lh[t] ? (t * CAPU + atomicAdd(&zcur[t], lh[t])) : 0;
    __syncthreads();
    #pragma unroll
    for (int k = 0; k < 16; ++k)
        if (rnk[k] >= 0) {
            int2 p; p.x = recx[k]; p.y = recy[k];
            binbuf[lbase[bkt[k]] + rnk[k]] = p;
        }
}

__device__ void dev_disen_cor(const float* __restrict__ att,
                              const float* __restrict__ weight,
                              float* __restrict__ dw, float* __restrict__ cor_out) {
    int tid = threadIdx.x;
    int f = tid >> 6, c = tid & 63;
    float m = -1e30f;
    for (int r = 0; r < N_REL; ++r) m = fmaxf(m, att[f * N_REL + r]);
    float e[N_REL], s = 0.0f;
    for (int r = 0; r < N_REL; ++r) { e[r] = __expf(att[f * N_REL + r] - m); s += e[r]; }
    float acc = 0.0f;
    for (int r = 0; r < N_REL; ++r) acc += (e[r] / s) * weight[r * CDIM + c];
    dw[f * CDIM + c] = acc;

    if (tid == 0) {
        float rowsum[N_FACTORS];
        for (int ff = 0; ff < N_FACTORS; ++ff) {
            float ss = 0.0f;
            for (int j = 0; j < N_REL; ++j) ss += att[ff * N_REL + j];
            rowsum[ff] = ss;
        }
        float cor = 0.0f;
        for (int i = 0; i < N_REL; ++i) {
            float nsq = 0.0f, ttl = 0.0f;
            for (int ff = 0; ff < N_FACTORS; ++ff) {
                float a = att[ff * N_REL + i];
                nsq += a * a;
                ttl += a * rowsum[ff];
            }
            float n = sqrtf(nsq);
            float pos = 0.0f;
            for (int ff = 0; ff < N_FACTORS; ++ff) {
                float a = att[ff * N_REL + i] / n;
                pos += a * a;
            }
            cor += (ttl - pos) / TEMP;
        }
        *cor_out = cor;
    }
}

__global__ __launch_bounds__(256) void prep_kernel(const float* __restrict__ entity_emb,
                                                   u8* __restrict__ ef8,
                                                   const int* __restrict__ head,
                                                   const int* __restrict__ tail,
                                                   const int* __restrict__ etype,
                                                   const int* __restrict__ rows,
                                                   const int* __restrict__ cols,
                                                   const float* __restrict__ vals,
                                                   int* __restrict__ zce, int* __restrict__ zcu,
                                                   int* __restrict__ bine, int2* __restrict__ binu,
                                                   const float* __restrict__ att,
                                                   const float* __restrict__ weight,
                                                   float* __restrict__ dw,
                                                   float* __restrict__ cor_out) {
    int bid = blockIdx.x;
    if (bid < GCVT)                 dev_cvt(bid, entity_emb, ef8);
    else if (bid < GCVT + GA)       dev_bin_edges(bid - GCVT, head, tail, etype, zce, bine);
    else if (bid < GCVT + 2 * GA)   dev_bin_inter(bid - GCVT - GA, rows, cols, vals, zcu, binu);
    else                            dev_disen_cor(att, weight, dw, cor_out);
}

// ============ kernel B: per-bucket CSR finalize -> padded epk/ucv + info =====
__device__ void dev_build_e(int b, const int* __restrict__ zce,
                            const int* __restrict__ binbuf,
                            int2* __restrict__ einfo, int* __restrict__ epk,
                            int* __restrict__ dbinE) {
    __shared__ int lh[CB];
    __shared__ int ss[256];
    __shared__ int ldeg[64];
    int t = threadIdx.x;
    int bstart = b * CAPE;
    int bend = bstart + zce[b];
    #pragma unroll
    for (int k = 0; k < 4; ++k) lh[t * 4 + k] = 0;
    if (t < 64) ldeg[t] = 0;
    __syncthreads();
    for (int j = bstart + t; j < bend; j += 256)
        atomicAdd(&lh[(u32)binbuf[j] >> 22], 1);
    __syncthreads();
    int v[4], acc = 0;
    #pragma unroll
    for (int k = 0; k < 4; ++k) { v[k] = lh[t * 4 + k]; acc += v[k]; }
    ss[t] = acc; __syncthreads();
    #pragma unroll
    for (int d = 1; d < 256; d <<= 1) {
        int x = (t >= d) ? ss[t - d] : 0;
        __syncthreads();
        ss[t] += x;
        __syncthreads();
    }
    int excl = ss[t] - acc;
    int hbase = b * CB;
    #pragma unroll
    for (int k = 0; k < 4; ++k) {
        int hl = t * 4 + k;
        int h = hbase + hl;
        if (h < N_ENTITIES) {
            int2 inf; inf.x = bstart + excl; inf.y = v[k];
            einfo[h] = inf;
            atomicAdd(&ldeg[63 - min(v[k], 63)], 1);   // descending-degree bins
        }
        lh[hl] = excl;
        excl += v[k];
    }
    __syncthreads();
    if (t < 64 && ldeg[t]) atomicAdd(&dbinE[t], ldeg[t]);
    for (int j = bstart + t; j < bend; j += 256) {
        int rec = binbuf[j];
        int pos = atomicAdd(&lh[(u32)rec >> 22], 1);
        epk[bstart + pos] = rec & 0x3FFFFF;   // rel<<18 | tail
    }
}

__device__ void dev_build_u(int b, const int* __restrict__ zcu,
                            const int2* __restrict__ binbuf,
                            int2* __restrict__ uinfo, int2* __restrict__ ucv,
                            int* __restrict__ dbinU) {
    __shared__ int lh[CB];
    __shared__ int ss[256];
    __shared__ int ldeg[64];
    int t = threadIdx.x;
    int bstart = b * CAPU;
    int bend = bstart + zcu[b];
    #pragma unroll
    for (int k = 0; k < 4; ++k) lh[t * 4 + k] = 0;
    if (t < 64) ldeg[t] = 0;
    __syncthreads();
    for (int j = bstart + t; j < bend; j += 256)
        atomicAdd(&lh[(u32)binbuf[j].x >> 18], 1);
    __syncthreads();
    int v[4], acc = 0;
    #pragma unroll
    for (int k = 0; k < 4; ++k) { v[k] = lh[t * 4 + k]; acc += v[k]; }
    ss[t] = acc; __syncthreads();
    #pragma unroll
    for (int d = 1; d < 256; d <<= 1) {
        int x = (t >= d) ? ss[t - d] : 0;
        __syncthreads();
        ss[t] += x;
        __syncthreads();
    }
    int excl = ss[t] - acc;
    int ubase = b * CB;
    #pragma unroll
    for (int k = 0; k < 4; ++k) {
        int ul = t * 4 + k;
        int u = ubase + ul;
        if (u < N_USERS) {
            int2 inf; inf.x = bstart + excl; inf.y = v[k];
            uinfo[u] = inf;
            atomicAdd(&ldeg[63 - min(v[k], 63)], 1);
        }
        lh[ul] = excl;
        excl += v[k];
    }
    __syncthreads();
    if (t < 64 && ldeg[t]) atomicAdd(&dbinU[t], ldeg[t]);
    for (int j = bstart + t; j < bend; j += 256) {
        int2 rec = binbuf[j];
        int pos = atomicAdd(&lh[(u32)rec.x >> 18], 1);
        int2 out; out.x = rec.x & 0x3FFFF; out.y = rec.y;
        ucv[bstart + pos] = out;
    }
}

__global__ __launch_bounds__(256) void build_kernel(const int* __restrict__ zce,
                                                    const int* __restrict__ zcu,
                                                    const int* __restrict__ bine,
                                                    const int2* __restrict__ binu,
                                                    int2* __restrict__ einfo, int* __restrict__ epk,
                                                    int2* __restrict__ uinfo, int2* __restrict__ ucv,
                                                    int* __restrict__ dbinE, int* __restrict__ dbinU) {
    int bid = blockIdx.x;
    if (bid < NBE) dev_build_e(bid, zce, bine, einfo, epk, dbinE);
    else           dev_build_u(bid - NBE, zcu, binu, uinfo, ucv, dbinU);
}

// ============ kernel C: degree-sorted permutation ============================
__device__ void dev_perm(int b, int n, const int2* __restrict__ info,
                         const int* __restrict__ dbin,
                         int* __restrict__ zdeg, int2* __restrict__ perm) {
    __shared__ int dbase[64], dtmp[64];
    __shared__ int lh[64], lbase[64];
    int t = threadIdx.x;
    if (t < 64) { dtmp[t] = dbin[t]; lh[t] = 0; }
    __syncthreads();
    if (t < 64) {
        int v = dtmp[t];
        #pragma unroll
        for (int d = 1; d < 64; d <<= 1) {
            int x = (t >= d) ? dtmp[t - d] : 0;
            __syncthreads();
            dtmp[t] += x;
            __syncthreads();
        }
        dbase[t] = dtmp[t] - v;
    } else {
        #pragma unroll
        for (int d = 1; d < 64; d <<= 1) { __syncthreads(); __syncthreads(); }
    }
    __syncthreads();
    int base = b * PCHUNK;
    int rnk[16], bin[16], deg[16], st[16];
    #pragma unroll
    for (int k = 0; k < 16; ++k) {
        int i = base + k * 256 + t;
        rnk[k] = -1;
        if (i < n) {
            int2 q = info[i];
            deg[k] = q.y; st[k] = q.x;
            bin[k] = 63 - min(deg[k], 63);     // descending degree
            rnk[k] = atomicAdd(&lh[bin[k]], 1);
        }
    }
    __syncthreads();
    if (t < 64) lbase[t] = lh[t] ? (dbase[t] + atomicAdd(&zdeg[t], lh[t])) : 0;
    __syncthreads();
    #pragma unroll
    for (int k = 0; k < 16; ++k)
        if (rnk[k] >= 0) {
            int i = base + k * 256 + t;
            int2 p;
            p.x = (int)(((u32)min(deg[k], 16383) << 18) | (u32)i);
            p.y = st[k];
            perm[lbase[bin[k]] + rnk[k]] = p;
        }
}

__global__ __launch_bounds__(256) void perm_kernel(const int2* __restrict__ einfo,
                                                   const int2* __restrict__ uinfo,
                                                   const int* __restrict__ dbinE,
                                                   const int* __restrict__ dbinU,
                                                   int* __restrict__ zdegE, int* __restrict__ zdegU,
                                                   int2* __restrict__ permE, int2* __restrict__ permU) {
    int bid = blockIdx.x;
    if (bid < GPE) dev_perm(bid, N_ENTITIES, einfo, dbinE, zdegE, permE);
    else           dev_perm(bid - GPE, N_USERS, uinfo, dbinU, zdegU, permU);
}

// ============ hop kernels (kg + user), 4-deep pipelined gather ===============
__device__ void dev_kg_hop(int widg, const u8* __restrict__ esrc,
                           const int2* __restrict__ permE,
                           const int* __restrict__ epk,
                           const float* __restrict__ weight,
                           const float* __restrict__ emb0,
                           u8* __restrict__ enew, float* __restrict__ eres, int last) {
    int lane = threadIdx.x & 63;
    int slot = lane >> 3, seg = lane & 7;
    int2 pe = permE[widg * 8 + slot];
    u32 px = (u32)pe.x;
    int d = px >> 18, h = (int)(px & 0x3FFFFu), s = pe.y;
    int dmax = d;
    dmax = max(dmax, __shfl_xor(dmax, 8, 64));
    dmax = max(dmax, __shfl_xor(dmax, 16, 64));
    dmax = max(dmax, __shfl_xor(dmax, 32, 64));

    float acc[8];
    #pragma unroll
    for (int k = 0; k < 8; ++k) acc[k] = 0.0f;
    const uint2 uz = make_uint2(0u, 0u);

    for (int it = 0; it < dmax; it += 4) {
        int pk[4]; uint2 rv[4];
        #pragma unroll
        for (int q = 0; q < 4; ++q)
            pk[q] = (it + q < d) ? epk[s + it + q] : 0;
        #pragma unroll
        for (int q = 0; q < 4; ++q)
            rv[q] = (it + q < d)
                  ? *(const uint2*)(esrc + (size_t)(pk[q] & 0x3FFFF) * CDIM + seg * 8) : uz;
        #pragma unroll
        for (int q = 0; q < 4; ++q)
            fma_rowW(acc, rv[q], pk[q] >> 18, weight, seg);
    }
    float inv = 1.0f / fmaxf((float)d, 1.0f);
    float ssq = 0.0f;
    #pragma unroll
    for (int k = 0; k < 8; ++k) { acc[k] *= inv; ssq += acc[k] * acc[k]; }
    ssq += __shfl_xor(ssq, 1, 64);
    ssq += __shfl_xor(ssq, 2, 64);
    ssq += __shfl_xor(ssq, 4, 64);
    float rn = 1.0f / fmaxf(sqrtf(ssq), 1e-12f);
    #pragma unroll
    for (int k = 0; k < 8; ++k) acc[k] *= rn;

    size_t base = (size_t)h * CDIM + seg * 8;
    if (!last) {
        *(uint2*)(enew + base) = pack8_fp8(acc);
    } else {
        uint2 pv = *(const uint2*)(esrc + base);   // esrc == hop0 output eA (fp8)
        float o0[8]; unpack8_fp8(pv, o0);
        float4 a = *(const float4*)(emb0 + base);
        float4 b = *(const float4*)(emb0 + base + 4);
        float4 r0, r1;
        r0.x = a.x + o0[0] + acc[0]; r0.y = a.y + o0[1] + acc[1];
        r0.z = a.z + o0[2] + acc[2]; r0.w = a.w + o0[3] + acc[3];
        r1.x = b.x + o0[4] + acc[4]; r1.y = b.y + o0[5] + acc[5];
        r1.z = b.z + o0[6] + acc[6]; r1.w = b.w + o0[7] + acc[7];
        *(float4*)(eres + base) = r0;
        *(float4*)(eres + base + 4) = r1;
    }
}

__device__ void dev_user_hop(int widg, const float* __restrict__ uoldf,
                             const u16* __restrict__ uoldb,
                             const u8* __restrict__ esrc,
                             const int2* __restrict__ permU,
                             const int2* __restrict__ ucv,
                             const float* __restrict__ latent,
                             const float* __restrict__ dw,
                             const float* __restrict__ uemb0,
                             u16* __restrict__ unew, float* __restrict__ ures, int last) {
    int lane = threadIdx.x & 63;
    int slot = lane >> 3, seg = lane & 7;
    int2 pe = permU[widg * 8 + slot];
    u32 px = (u32)pe.x;
    int d = px >> 18, u = (int)(px & 0x3FFFFu), s = pe.y;
    int dmax = d;
    dmax = max(dmax, __shfl_xor(dmax, 8, 64));
    dmax = max(dmax, __shfl_xor(dmax, 16, 64));
    dmax = max(dmax, __shfl_xor(dmax, 32, 64));

    float acc[8];
    #pragma unroll
    for (int k = 0; k < 8; ++k) acc[k] = 0.0f;
    const uint2 uz = make_uint2(0u, 0u);
    const int2 cz = make_int2(0, 0);

    for (int it = 0; it < dmax; it += 4) {
        int2 cc[4]; uint2 rv[4];
        #pragma unroll
        for (int q = 0; q < 4; ++q)
            cc[q] = (it + q < d) ? ucv[s + it + q] : cz;
        #pragma unroll
        for (int q = 0; q < 4; ++q)
            rv[q] = (it + q < d)
                  ? *(const uint2*)(esrc + (size_t)cc[q].x * CDIM + seg * 8) : uz;
        #pragma unroll
        for (int q = 0; q < 4; ++q)
            fma_rowV(acc, rv[q], __int_as_float(cc[q].y));
    }

    float uo[8];
    size_t ubase = (size_t)u * CDIM + seg * 8;
    if (uoldb) {
        uint4 pv = *(const uint4*)(uoldb + ubase);
        unpack8_bf(pv, uo);
    } else {
        float4 a = *(const float4*)(uoldf + ubase);
        float4 b = *(const float4*)(uoldf + ubase + 4);
        uo[0] = a.x; uo[1] = a.y; uo[2] = a.z; uo[3] = a.w;
        uo[4] = b.x; uo[5] = b.y; uo[6] = b.z; uo[7] = b.w;
    }
    float dts[N_FACTORS];
    #pragma unroll
    for (int f = 0; f < N_FACTORS; ++f) {
        const float4* lp = (const float4*)(latent + f * CDIM + seg * 8);
        float4 l0 = lp[0], l1 = lp[1];
        float p = uo[0] * l0.x + uo[1] * l0.y + uo[2] * l0.z + uo[3] * l0.w +
                  uo[4] * l1.x + uo[5] * l1.y + uo[6] * l1.z + uo[7] * l1.w;
        p += __shfl_xor(p, 1, 64);
        p += __shfl_xor(p, 2, 64);
        p += __shfl_xor(p, 4, 64);
        dts[f] = p;
    }
    float m = fmaxf(fmaxf(dts[0], dts[1]), fmaxf(dts[2], dts[3]));
    float e0 = __expf(dts[0] - m), e1 = __expf(dts[1] - m);
    float e2 = __expf(dts[2] - m), e3 = __expf(dts[3] - m);
    float inv_ssum = 1.0f / (e0 + e1 + e2 + e3);
    e0 *= inv_ssum; e1 *= inv_ssum; e2 *= inv_ssum; e3 *= inv_ssum;

    const float4* d0p = (const float4*)(dw + 0 * CDIM + seg * 8);
    const float4* d1p = (const float4*)(dw + 1 * CDIM + seg * 8);
    const float4* d2p = (const float4*)(dw + 2 * CDIM + seg * 8);
    const float4* d3p = (const float4*)(dw + 3 * CDIM + seg * 8);
    float4 ga0 = d0p[0], ga1 = d0p[1];
    float4 gb0 = d1p[0], gb1 = d1p[1];
    float4 gc0 = d2p[0], gc1 = d2p[1];
    float4 gd0 = d3p[0], gd1 = d3p[1];
    float g[8];
    g[0] = e0 * ga0.x + e1 * gb0.x + e2 * gc0.x + e3 * gd0.x;
    g[1] = e0 * ga0.y + e1 * gb0.y + e2 * gc0.y + e3 * gd0.y;
    g[2] = e0 * ga0.z + e1 * gb0.z + e2 * gc0.z + e3 * gd0.z;
    g[3] = e0 * ga0.w + e1 * gb0.w + e2 * gc0.w + e3 * gd0.w;
    g[4] = e0 * ga1.x + e1 * gb1.x + e2 * gc1.x + e3 * gd1.x;
    g[5] = e0 * ga1.y + e1 * gb1.y + e2 * gc1.y + e3 * gd1.y;
    g[6] = e0 * ga1.z + e1 * gb1.z + e2 * gc1.z + e3 * gd1.z;
    g[7] = e0 * ga1.w + e1 * gb1.w + e2 * gc1.w + e3 * gd1.w;

    float ssq = 0.0f;
    #pragma unroll
    for (int k = 0; k < 8; ++k) {
        acc[k] = acc[k] * (1.0f + g[k]);
        ssq += acc[k] * acc[k];
    }
    ssq += __shfl_xor(ssq, 1, 64);
    ssq += __shfl_xor(ssq, 2, 64);
    ssq += __shfl_xor(ssq, 4, 64);
    float rn = 1.0f / fmaxf(sqrtf(ssq), 1e-12f);
    #pragma unroll
    for (int k = 0; k < 8; ++k) acc[k] *= rn;

    if (!last) {
        *(uint4*)(unew + ubase) = pack8_bf(acc);
    } else {
        float4 a = *(const float4*)(uemb0 + ubase);
        float4 b = *(const float4*)(uemb0 + ubase + 4);
        float4 r0, r1;
        r0.x = a.x + uo[0] + acc[0]; r0.y = a.y + uo[1] + acc[1];
        r0.z = a.z + uo[2] + acc[2]; r0.w = a.w + uo[3] + acc[3];
        r1.x = b.x + uo[4] + acc[4]; r1.y = b.y + uo[5] + acc[5];
        r1.z = b.z + uo[6] + acc[6]; r1.w = b.w + uo[7] + acc[7];
        *(float4*)(ures + ubase) = r0;
        *(float4*)(ures + ubase + 4) = r1;
    }
}

__global__ __launch_bounds__(256) void hop_kernel(const u8* __restrict__ e_src,
                                                  const int2* __restrict__ permE,
                                                  const int* __restrict__ epk,
                                                  const float* __restrict__ weight,
                                                  const float* __restrict__ entity_emb,
                                                  u8* __restrict__ eA,
                                                  float* __restrict__ eres,
                                                  const float* __restrict__ uoldf,
                                                  const u16* __restrict__ uoldb,
                                                  const int2* __restrict__ permU,
                                                  const int2* __restrict__ ucv,
                                                  const float* __restrict__ latent,
                                                  const float* __restrict__ dw,
                                                  const float* __restrict__ user_emb,
                                                  u16* __restrict__ uA,
                                                  float* __restrict__ ures,
                                                  int last) {
    int bid = blockIdx.x;
    int wave = threadIdx.x >> 6;
    if (bid < KG_BLOCKS) {
        dev_kg_hop(bid * 4 + wave, e_src, permE, epk, weight, entity_emb, eA, eres, last);
    } else {
        dev_user_hop((bid - KG_BLOCKS) * 4 + wave, uoldf, uoldb, e_src, permU, ucv,
                     latent, dw, user_emb, uA, ures, last);
    }
}

static inline size_t align16(size_t x) { return (x + 15) & ~(size_t)15; }

extern "C" void kernel_launch(void* const* d_in, const int* in_sizes, int n_in,
                              void* d_out, int out_size, void* d_ws, size_t ws_size,
                              hipStream_t stream) {
    const float* user_emb   = (const float*)d_in[0];
    const float* entity_emb = (const float*)d_in[1];
    const float* latent_emb = (const float*)d_in[2];
    const float* weight     = (const float*)d_in[3];
    const float* att        = (const float*)d_in[4];
    const int*   edge_index = (const int*)d_in[5];
    const int*   edge_type  = (const int*)d_in[6];
    const int*   inter_rows = (const int*)d_in[7];
    const int*   inter_cols = (const int*)d_in[8];
    const float* inter_vals = (const float*)d_in[9];

    float* eres = (float*)d_out;
    float* ures = eres + (size_t)N_ENTITIES * CDIM;
    float* cor  = ures + (size_t)N_USERS * CDIM;

    char* ws = (char*)d_ws;
    u8*    ef8   = (u8*)ws;   ws += align16(sizeof(u8) * (size_t)N_ENTITIES * CDIM);
    u8*    eA    = (u8*)ws;   ws += align16(sizeof(u8) * (size_t)N_ENTITIES * CDIM);
    u16*   uA    = (u16*)ws;  ws += align16(sizeof(u16) * (size_t)N_USERS * CDIM);
    int*   epk   = (int*)ws;  ws += align16(sizeof(int) * (size_t)NBE * CAPE);
    int2*  ucv   = (int2*)ws; ws += align16(sizeof(int2) * (size_t)NBU * CAPU);
    int*   bine  = (int*)ws;  ws += align16(sizeof(int) * (size_t)NBE * CAPE);
    int2*  binu  = (int2*)ws; ws += align16(sizeof(int2) * (size_t)NBU * CAPU);
    int2*  einfo = (int2*)ws; ws += align16(sizeof(int2) * N_ENTITIES);
    int2*  uinfo = (int2*)ws; ws += align16(sizeof(int2) * N_USERS);
    int*   ctrs  = (int*)ws;  ws += align16(sizeof(int) * 768);
    int2*  permE = (int2*)ws; ws += align16(sizeof(int2) * N_ENTITIES);
    int2*  permU = (int2*)ws; ws += align16(sizeof(int2) * N_USERS);
    float* dw    = (float*)ws; ws += align16(sizeof(float) * N_FACTORS * CDIM);

    // counter layout (one small memset zeroes everything)
    int* zce   = ctrs;          // 256: bin cursors (entity buckets)
    int* zcu   = ctrs + 256;    // 256: bin cursors (user buckets)
    int* dbinE = ctrs + 512;    // 64
    int* dbinU = ctrs + 576;    // 64
    int* zdegE = ctrs + 640;    // 64
    int* zdegU = ctrs + 704;    // 64

    const int* head = edge_index;
    const int* tail = edge_index + N_EDGES;

    (void)hipMemsetAsync(ctrs, 0, sizeof(int) * 768, stream);

    prep_kernel<<<GCVT + 2 * GA + 1, 256, 0, stream>>>(
        entity_emb, ef8, head, tail, edge_type,
        inter_rows, inter_cols, inter_vals,
        zce, zcu, bine, binu, att, weight, dw, cor);
    build_kernel<<<NBE + NBU, 256, 0, stream>>>(zce, zcu, bine, binu,
                                                einfo, epk, uinfo, ucv, dbinE, dbinU);
    perm_kernel<<<GPE + GPU_, 256, 0, stream>>>(einfo, uinfo, dbinE, dbinU,
                                                zdegE, zdegU, permE, permU);

    // hop 0: gather from ef8; write fp8 eA + bf16 uA
    hop_kernel<<<KG_BLOCKS + USER_BLOCKS, 256, 0, stream>>>(
        ef8, permE, epk, weight, entity_emb, eA, eres,
        user_emb, (const u16*)nullptr, permU, ucv, latent_emb, dw, user_emb, uA, ures, 0);
    // hop 1: gather from eA; write res = emb0 + o0 + o1
    hop_kernel<<<KG_BLOCKS + USER_BLOCKS, 256, 0, stream>>>(
        eA, permE, epk, weight, entity_emb, (u8*)nullptr, eres,
        (const float*)nullptr, uA, permU, ucv, latent_emb, dw, user_emb, (u16*)nullptr, ures, 1);
}

// Round 14
// 201.580 us; speedup vs baseline: 1.1062x; 1.0116x over previous
//
#include <hip/hip_runtime.h>
#include <math.h>

#define N_USERS    100000
#define N_ENTITIES 200000
#define N_EDGES    1000000
#define NNZ        1000000
#define CDIM       64
#define N_FACTORS  4
#define N_REL      10
#define TEMP       0.2f

#define CB         1024
#define NBE        196      // ceil(200000/1024)
#define NBU        98       // ceil(100000/1024)
#define CAPE       8192     // padded edges per entity bucket
#define CAPU       12288    // padded nnz per user bucket
#define ACHUNK     4096
#define GA         245      // ceil(1e6/4096)
#define GCVT       6250     // (200000*64/8)/256
#define KG_BLOCKS  6250     // 200000 / 32 rows per block
#define USER_BLOCKS 3125    // 100000 / 32
#define PCHUNK     4096
#define GPE        49       // ceil(200000/4096)
#define GPU_       25       // ceil(100000/4096)

typedef unsigned int u32;
typedef unsigned short u16;
typedef unsigned char u8;

#if defined(__has_builtin)
#if __has_builtin(__builtin_amdgcn_cvt_pk_f32_fp8) && __has_builtin(__builtin_amdgcn_cvt_pk_fp8_f32)
#define HAVE_HW_FP8 1
#endif
#endif

// ---- bf16 helpers ----------------------------------------------------------
__device__ __forceinline__ float bflo(u32 w) { return __uint_as_float(w << 16); }
__device__ __forceinline__ float bfhi(u32 w) { return __uint_as_float(w & 0xFFFF0000u); }
__device__ __forceinline__ u16 f2bf(float f) {
    u32 u = __float_as_uint(f);
    u32 r = u + 0x7FFFu + ((u >> 16) & 1u);   // RNE
    return (u16)(r >> 16);
}
__device__ __forceinline__ void unpack8_bf(uint4 rv, float* x) {
    x[0] = bflo(rv.x); x[1] = bfhi(rv.x);
    x[2] = bflo(rv.y); x[3] = bfhi(rv.y);
    x[4] = bflo(rv.z); x[5] = bfhi(rv.z);
    x[6] = bflo(rv.w); x[7] = bfhi(rv.w);
}
__device__ __forceinline__ uint4 pack8_bf(const float* x) {
    uint4 o;
    o.x = (u32)f2bf(x[0]) | ((u32)f2bf(x[1]) << 16);
    o.y = (u32)f2bf(x[2]) | ((u32)f2bf(x[3]) << 16);
    o.z = (u32)f2bf(x[4]) | ((u32)f2bf(x[5]) << 16);
    o.w = (u32)f2bf(x[6]) | ((u32)f2bf(x[7]) << 16);
    return o;
}

// ---- fp8 e4m3 helpers ------------------------------------------------------
#ifndef HAVE_HW_FP8
__device__ __forceinline__ float fp8_dec1(u32 b) {
    u32 s = b >> 7, em = b & 0x7F;
    float mag;
    if (em < 8) mag = (float)em * 0.001953125f;                      // subnormal, 2^-9
    else {
        u32 bits = (((em >> 3) + 120u) << 23) | ((em & 7u) << 20);
        mag = __uint_as_float(bits);
    }
    return s ? -mag : mag;
}
__device__ __forceinline__ u32 fp8_enc1(float f) {
    float a = fabsf(f);
    u32 s = (__float_as_uint(f) >> 31) << 7;
    if (a < 0.015625f) {
        int n = (int)rintf(a * 512.0f);                              // 0..8
        return s | (u32)n;
    }
    u32 u = __float_as_uint(a);
    u32 r = u + 0x0007FFFFu + ((u >> 20) & 1u);                      // RNE at bit 20
    int ee = (int)((r >> 23) & 0xFF) - 127 + 7;
    if (ee >= 16) return s | 0x7Eu;                                  // clamp to 448
    return s | ((u32)ee << 3) | ((r >> 20) & 7u);
}
#endif

__device__ __forceinline__ void unpack8_fp8(uint2 rv, float* x) {
#ifdef HAVE_HW_FP8
    typedef float floatx2 __attribute__((ext_vector_type(2)));
    floatx2 a0 = __builtin_amdgcn_cvt_pk_f32_fp8(rv.x, false);
    floatx2 a1 = __builtin_amdgcn_cvt_pk_f32_fp8(rv.x, true);
    floatx2 a2 = __builtin_amdgcn_cvt_pk_f32_fp8(rv.y, false);
    floatx2 a3 = __builtin_amdgcn_cvt_pk_f32_fp8(rv.y, true);
    x[0] = a0.x; x[1] = a0.y; x[2] = a1.x; x[3] = a1.y;
    x[4] = a2.x; x[5] = a2.y; x[6] = a3.x; x[7] = a3.y;
#else
    x[0] = fp8_dec1(rv.x & 0xFF);         x[1] = fp8_dec1((rv.x >> 8) & 0xFF);
    x[2] = fp8_dec1((rv.x >> 16) & 0xFF); x[3] = fp8_dec1(rv.x >> 24);
    x[4] = fp8_dec1(rv.y & 0xFF);         x[5] = fp8_dec1((rv.y >> 8) & 0xFF);
    x[6] = fp8_dec1((rv.y >> 16) & 0xFF); x[7] = fp8_dec1(rv.y >> 24);
#endif
}
__device__ __forceinline__ uint2 pack8_fp8(const float* x) {
    uint2 o;
#ifdef HAVE_HW_FP8
    int v0 = 0, v1 = 0;
    v0 = __builtin_amdgcn_cvt_pk_fp8_f32(x[0], x[1], v0, false);
    v0 = __builtin_amdgcn_cvt_pk_fp8_f32(x[2], x[3], v0, true);
    v1 = __builtin_amdgcn_cvt_pk_fp8_f32(x[4], x[5], v1, false);
    v1 = __builtin_amdgcn_cvt_pk_fp8_f32(x[6], x[7], v1, true);
    o.x = (u32)v0; o.y = (u32)v1;
#else
    o.x = fp8_enc1(x[0]) | (fp8_enc1(x[1]) << 8) | (fp8_enc1(x[2]) << 16) | (fp8_enc1(x[3]) << 24);
    o.y = fp8_enc1(x[4]) | (fp8_enc1(x[5]) << 8) | (fp8_enc1(x[6]) << 16) | (fp8_enc1(x[7]) << 24);
#endif
    return o;
}

__device__ __forceinline__ void fma_rowW(float* acc, uint2 rv, int rel,
                                         const float* __restrict__ weight, int seg) {
    float x[8]; unpack8_fp8(rv, x);
    const float4* wp = (const float4*)(weight + rel * CDIM + seg * 8);
    float4 w0 = wp[0], w1 = wp[1];
    acc[0] += x[0] * w0.x; acc[1] += x[1] * w0.y;
    acc[2] += x[2] * w0.z; acc[3] += x[3] * w0.w;
    acc[4] += x[4] * w1.x; acc[5] += x[5] * w1.y;
    acc[6] += x[6] * w1.z; acc[7] += x[7] * w1.w;
}
__device__ __forceinline__ void fma_rowV(float* acc, uint2 rv, float v) {
    float x[8]; unpack8_fp8(rv, x);
    #pragma unroll
    for (int k = 0; k < 8; ++k) acc[k] += v * x[k];
}

// ============ kernel A: cvt(f32->fp8) + direct bin passes + disen/cor ========
__device__ void dev_cvt(int b, const float* __restrict__ in, u8* __restrict__ out) {
    int i = b * 256 + threadIdx.x;
    const float4* p = (const float4*)(in + (size_t)i * 8);
    float4 a = p[0], bb = p[1];
    float x[8] = {a.x, a.y, a.z, a.w, bb.x, bb.y, bb.z, bb.w};
    *(uint2*)(out + (size_t)i * 8) = pack8_fp8(x);
}

// direct bin of edges into padded per-bucket regions (no pre-histogram)
__device__ void dev_bin_edges(int b, const int* __restrict__ head,
                              const int* __restrict__ tail, const int* __restrict__ etype,
                              int* __restrict__ zcur, int* __restrict__ binbuf) {
    __shared__ int lh[256], lbase[256];
    int t = threadIdx.x;
    lh[t] = 0; __syncthreads();
    int base = b * ACHUNK;
    int rec[16], rnk[16], bkt[16];
    #pragma unroll
    for (int k = 0; k < 16; ++k) {
        int i = base + k * 256 + t;
        rnk[k] = -1; rec[k] = 0; bkt[k] = 0;
        if (i < N_EDGES) {
            int h = head[i];
            bkt[k] = h >> 10;
            rec[k] = ((h & 1023) << 22) | ((etype[i] - 1) << 18) | tail[i];
            rnk[k] = atomicAdd(&lh[bkt[k]], 1);
        }
    }
    __syncthreads();
    lbase[t] = lh[t] ? (t * CAPE + atomicAdd(&zcur[t], lh[t])) : 0;
    __syncthreads();
    #pragma unroll
    for (int k = 0; k < 16; ++k)
        if (rnk[k] >= 0) binbuf[lbase[bkt[k]] + rnk[k]] = rec[k];
}

__device__ void dev_bin_inter(int b, const int* __restrict__ rows,
                              const int* __restrict__ cols, const float* __restrict__ vals,
                              int* __restrict__ zcur, int2* __restrict__ binbuf) {
    __shared__ int lh[256], lbase[256];
    int t = threadIdx.x;
    lh[t] = 0; __syncthreads();
    int base = b * ACHUNK;
    int recx[16], recy[16], rnk[16], bkt[16];
    #pragma unroll
    for (int k = 0; k < 16; ++k) {
        int i = base + k * 256 + t;
        rnk[k] = -1; recx[k] = 0; recy[k] = 0; bkt[k] = 0;
        if (i < NNZ) {
            int r = rows[i];
            bkt[k] = r >> 10;
            recx[k] = ((r & 1023) << 18) | cols[i];
            recy[k] = __float_as_int(vals[i]);
            rnk[k] = atomicAdd(&lh[bkt[k]], 1);
        }
    }
    __syncthreads();
    lbase[t] = lh[t] ? (t * CAPU + atomicAdd(&zcur[t], lh[t])) : 0;
    __syncthreads();
    #pragma unroll
    for (int k = 0; k < 16; ++k)
        if (rnk[k] >= 0) {
            int2 p; p.x = recx[k]; p.y = recy[k];
            binbuf[lbase[bkt[k]] + rnk[k]] = p;
        }
}

__device__ void dev_disen_cor(const float* __restrict__ att,
                              const float* __restrict__ weight,
                              float* __restrict__ dw, float* __restrict__ cor_out) {
    int tid = threadIdx.x;
    int f = tid >> 6, c = tid & 63;
    float m = -1e30f;
    for (int r = 0; r < N_REL; ++r) m = fmaxf(m, att[f * N_REL + r]);
    float e[N_REL], s = 0.0f;
    for (int r = 0; r < N_REL; ++r) { e[r] = __expf(att[f * N_REL + r] - m); s += e[r]; }
    float acc = 0.0f;
    for (int r = 0; r < N_REL; ++r) acc += (e[r] / s) * weight[r * CDIM + c];
    dw[f * CDIM + c] = acc;

    if (tid == 0) {
        float rowsum[N_FACTORS];
        for (int ff = 0; ff < N_FACTORS; ++ff) {
            float ss = 0.0f;
            for (int j = 0; j < N_REL; ++j) ss += att[ff * N_REL + j];
            rowsum[ff] = ss;
        }
        float cor = 0.0f;
        for (int i = 0; i < N_REL; ++i) {
            float nsq = 0.0f, ttl = 0.0f;
            for (int ff = 0; ff < N_FACTORS; ++ff) {
                float a = att[ff * N_REL + i];
                nsq += a * a;
                ttl += a * rowsum[ff];
            }
            float n = sqrtf(nsq);
            float pos = 0.0f;
            for (int ff = 0; ff < N_FACTORS; ++ff) {
                float a = att[ff * N_REL + i] / n;
                pos += a * a;
            }
            cor += (ttl - pos) / TEMP;
        }
        *cor_out = cor;
    }
}

__global__ __launch_bounds__(256) void prep_kernel(const float* __restrict__ entity_emb,
                                                   u8* __restrict__ ef8,
                                                   const int* __restrict__ head,
                                                   const int* __restrict__ tail,
                                                   const int* __restrict__ etype,
                                                   const int* __restrict__ rows,
                                                   const int* __restrict__ cols,
                                                   const float* __restrict__ vals,
                                                   int* __restrict__ zce, int* __restrict__ zcu,
                                                   int* __restrict__ bine, int2* __restrict__ binu,
                                                   const float* __restrict__ att,
                                                   const float* __restrict__ weight,
                                                   float* __restrict__ dw,
                                                   float* __restrict__ cor_out) {
    int bid = blockIdx.x;
    if (bid < GCVT)                 dev_cvt(bid, entity_emb, ef8);
    else if (bid < GCVT + GA)       dev_bin_edges(bid - GCVT, head, tail, etype, zce, bine);
    else if (bid < GCVT + 2 * GA)   dev_bin_inter(bid - GCVT - GA, rows, cols, vals, zcu, binu);
    else                            dev_disen_cor(att, weight, dw, cor_out);
}

// ============ kernel B: per-bucket CSR finalize -> padded epk/ucv + info =====
__device__ void dev_build_e(int b, const int* __restrict__ zce,
                            const int* __restrict__ binbuf,
                            int2* __restrict__ einfo, int* __restrict__ epk,
                            int* __restrict__ dbinE) {
    __shared__ int lh[CB];
    __shared__ int ss[256];
    __shared__ int ldeg[64];
    int t = threadIdx.x;
    int bstart = b * CAPE;
    int bend = bstart + zce[b];
    #pragma unroll
    for (int k = 0; k < 4; ++k) lh[t * 4 + k] = 0;
    if (t < 64) ldeg[t] = 0;
    __syncthreads();
    for (int j = bstart + t; j < bend; j += 256)
        atomicAdd(&lh[(u32)binbuf[j] >> 22], 1);
    __syncthreads();
    int v[4], acc = 0;
    #pragma unroll
    for (int k = 0; k < 4; ++k) { v[k] = lh[t * 4 + k]; acc += v[k]; }
    ss[t] = acc; __syncthreads();
    #pragma unroll
    for (int d = 1; d < 256; d <<= 1) {
        int x = (t >= d) ? ss[t - d] : 0;
        __syncthreads();
        ss[t] += x;
        __syncthreads();
    }
    int excl = ss[t] - acc;
    int hbase = b * CB;
    #pragma unroll
    for (int k = 0; k < 4; ++k) {
        int hl = t * 4 + k;
        int h = hbase + hl;
        if (h < N_ENTITIES) {
            int2 inf; inf.x = bstart + excl; inf.y = v[k];
            einfo[h] = inf;
            atomicAdd(&ldeg[63 - min(v[k], 63)], 1);   // descending-degree bins
        }
        lh[hl] = excl;
        excl += v[k];
    }
    __syncthreads();
    if (t < 64 && ldeg[t]) atomicAdd(&dbinE[t], ldeg[t]);
    for (int j = bstart + t; j < bend; j += 256) {
        int rec = binbuf[j];
        int pos = atomicAdd(&lh[(u32)rec >> 22], 1);
        epk[bstart + pos] = rec & 0x3FFFFF;   // rel<<18 | tail
    }
}

__device__ void dev_build_u(int b, const int* __restrict__ zcu,
                            const int2* __restrict__ binbuf,
                            int2* __restrict__ uinfo, int2* __restrict__ ucv,
                            int* __restrict__ dbinU) {
    __shared__ int lh[CB];
    __shared__ int ss[256];
    __shared__ int ldeg[64];
    int t = threadIdx.x;
    int bstart = b * CAPU;
    int bend = bstart + zcu[b];
    #pragma unroll
    for (int k = 0; k < 4; ++k) lh[t * 4 + k] = 0;
    if (t < 64) ldeg[t] = 0;
    __syncthreads();
    for (int j = bstart + t; j < bend; j += 256)
        atomicAdd(&lh[(u32)binbuf[j].x >> 18], 1);
    __syncthreads();
    int v[4], acc = 0;
    #pragma unroll
    for (int k = 0; k < 4; ++k) { v[k] = lh[t * 4 + k]; acc += v[k]; }
    ss[t] = acc; __syncthreads();
    #pragma unroll
    for (int d = 1; d < 256; d <<= 1) {
        int x = (t >= d) ? ss[t - d] : 0;
        __syncthreads();
        ss[t] += x;
        __syncthreads();
    }
    int excl = ss[t] - acc;
    int ubase = b * CB;
    #pragma unroll
    for (int k = 0; k < 4; ++k) {
        int ul = t * 4 + k;
        int u = ubase + ul;
        if (u < N_USERS) {
            int2 inf; inf.x = bstart + excl; inf.y = v[k];
            uinfo[u] = inf;
            atomicAdd(&ldeg[63 - min(v[k], 63)], 1);
        }
        lh[ul] = excl;
        excl += v[k];
    }
    __syncthreads();
    if (t < 64 && ldeg[t]) atomicAdd(&dbinU[t], ldeg[t]);
    for (int j = bstart + t; j < bend; j += 256) {
        int2 rec = binbuf[j];
        int pos = atomicAdd(&lh[(u32)rec.x >> 18], 1);
        int2 out; out.x = rec.x & 0x3FFFF; out.y = rec.y;
        ucv[bstart + pos] = out;
    }
}

__global__ __launch_bounds__(256) void build_kernel(const int* __restrict__ zce,
                                                    const int* __restrict__ zcu,
                                                    const int* __restrict__ bine,
                                                    const int2* __restrict__ binu,
                                                    int2* __restrict__ einfo, int* __restrict__ epk,
                                                    int2* __restrict__ uinfo, int2* __restrict__ ucv,
                                                    int* __restrict__ dbinE, int* __restrict__ dbinU) {
    int bid = blockIdx.x;
    if (bid < NBE) dev_build_e(bid, zce, bine, einfo, epk, dbinE);
    else           dev_build_u(bid - NBE, zcu, binu, uinfo, ucv, dbinU);
}

// ============ kernel C: degree-sorted permutation ============================
__device__ void dev_perm(int b, int n, const int2* __restrict__ info,
                         const int* __restrict__ dbin,
                         int* __restrict__ zdeg, int2* __restrict__ perm) {
    __shared__ int dbase[64], dtmp[64];
    __shared__ int lh[64], lbase[64];
    int t = threadIdx.x;
    if (t < 64) { dtmp[t] = dbin[t]; lh[t] = 0; }
    __syncthreads();
    if (t < 64) {
        int v = dtmp[t];
        #pragma unroll
        for (int d = 1; d < 64; d <<= 1) {
            int x = (t >= d) ? dtmp[t - d] : 0;
            __syncthreads();
            dtmp[t] += x;
            __syncthreads();
        }
        dbase[t] = dtmp[t] - v;
    } else {
        #pragma unroll
        for (int d = 1; d < 64; d <<= 1) { __syncthreads(); __syncthreads(); }
    }
    __syncthreads();
    int base = b * PCHUNK;
    int rnk[16], bin[16], deg[16], st[16];
    #pragma unroll
    for (int k = 0; k < 16; ++k) {
        int i = base + k * 256 + t;
        rnk[k] = -1;
        if (i < n) {
            int2 q = info[i];
            deg[k] = q.y; st[k] = q.x;
            bin[k] = 63 - min(deg[k], 63);     // descending degree
            rnk[k] = atomicAdd(&lh[bin[k]], 1);
        }
    }
    __syncthreads();
    if (t < 64) lbase[t] = lh[t] ? (dbase[t] + atomicAdd(&zdeg[t], lh[t])) : 0;
    __syncthreads();
    #pragma unroll
    for (int k = 0; k < 16; ++k)
        if (rnk[k] >= 0) {
            int i = base + k * 256 + t;
            int2 p;
            p.x = (int)(((u32)min(deg[k], 16383) << 18) | (u32)i);
            p.y = st[k];
            perm[lbase[bin[k]] + rnk[k]] = p;
        }
}

__global__ __launch_bounds__(256) void perm_kernel(const int2* __restrict__ einfo,
                                                   const int2* __restrict__ uinfo,
                                                   const int* __restrict__ dbinE,
                                                   const int* __restrict__ dbinU,
                                                   int* __restrict__ zdegE, int* __restrict__ zdegU,
                                                   int2* __restrict__ permE, int2* __restrict__ permU) {
    int bid = blockIdx.x;
    if (bid < GPE) dev_perm(bid, N_ENTITIES, einfo, dbinE, zdegE, permE);
    else           dev_perm(bid - GPE, N_USERS, uinfo, dbinU, zdegU, permU);
}

// ============ hop kernels (user first, kg second), 4-deep pipelined gather ===
__device__ void dev_kg_hop(int widg, const u8* __restrict__ esrc,
                           const int2* __restrict__ permE,
                           const int* __restrict__ epk,
                           const float* __restrict__ weight,
                           const float* __restrict__ emb0,
                           u8* __restrict__ enew, float* __restrict__ eres, int last) {
    int lane = threadIdx.x & 63;
    int slot = lane >> 3, seg = lane & 7;
    int2 pe = permE[widg * 8 + slot];
    u32 px = (u32)pe.x;
    int d = px >> 18, h = (int)(px & 0x3FFFFu), s = pe.y;
    // degree-sorted: slot 0 holds the wave's max degree
    int dmax = __shfl(d, (lane & 7), 64);    // lane's slot-0 partner (slots descend)

    float acc[8];
    #pragma unroll
    for (int k = 0; k < 8; ++k) acc[k] = 0.0f;
    const uint2 uz = make_uint2(0u, 0u);

    for (int it = 0; it < dmax; it += 4) {
        int pk[4]; uint2 rv[4];
        #pragma unroll
        for (int q = 0; q < 4; ++q)
            pk[q] = (it + q < d) ? epk[s + it + q] : 0;
        #pragma unroll
        for (int q = 0; q < 4; ++q)
            rv[q] = (it + q < d)
                  ? *(const uint2*)(esrc + (size_t)(pk[q] & 0x3FFFF) * CDIM + seg * 8) : uz;
        #pragma unroll
        for (int q = 0; q < 4; ++q)
            fma_rowW(acc, rv[q], pk[q] >> 18, weight, seg);
    }
    float inv = 1.0f / fmaxf((float)d, 1.0f);
    float ssq = 0.0f;
    #pragma unroll
    for (int k = 0; k < 8; ++k) { acc[k] *= inv; ssq += acc[k] * acc[k]; }
    ssq += __shfl_xor(ssq, 1, 64);
    ssq += __shfl_xor(ssq, 2, 64);
    ssq += __shfl_xor(ssq, 4, 64);
    float rn = 1.0f / fmaxf(sqrtf(ssq), 1e-12f);
    #pragma unroll
    for (int k = 0; k < 8; ++k) acc[k] *= rn;

    size_t base = (size_t)h * CDIM + seg * 8;
    if (!last) {
        *(uint2*)(enew + base) = pack8_fp8(acc);
    } else {
        uint2 pv = *(const uint2*)(esrc + base);   // esrc == hop0 output eA (fp8)
        float o0[8]; unpack8_fp8(pv, o0);
        float4 a = *(const float4*)(emb0 + base);
        float4 b = *(const float4*)(emb0 + base + 4);
        float4 r0, r1;
        r0.x = a.x + o0[0] + acc[0]; r0.y = a.y + o0[1] + acc[1];
        r0.z = a.z + o0[2] + acc[2]; r0.w = a.w + o0[3] + acc[3];
        r1.x = b.x + o0[4] + acc[4]; r1.y = b.y + o0[5] + acc[5];
        r1.z = b.z + o0[6] + acc[6]; r1.w = b.w + o0[7] + acc[7];
        *(float4*)(eres + base) = r0;
        *(float4*)(eres + base + 4) = r1;
    }
}

__device__ void dev_user_hop(int widg, const float* __restrict__ uoldf,
                             const u16* __restrict__ uoldb,
                             const u8* __restrict__ esrc,
                             const int2* __restrict__ permU,
                             const int2* __restrict__ ucv,
                             const float* __restrict__ latent,
                             const float* __restrict__ dw,
                             const float* __restrict__ uemb0,
                             u16* __restrict__ unew, float* __restrict__ ures, int last) {
    int lane = threadIdx.x & 63;
    int slot = lane >> 3, seg = lane & 7;
    int2 pe = permU[widg * 8 + slot];
    u32 px = (u32)pe.x;
    int d = px >> 18, u = (int)(px & 0x3FFFFu), s = pe.y;
    int dmax = __shfl(d, (lane & 7), 64);    // slot 0 has max degree

    float acc[8];
    #pragma unroll
    for (int k = 0; k < 8; ++k) acc[k] = 0.0f;
    const uint2 uz = make_uint2(0u, 0u);
    const int2 cz = make_int2(0, 0);

    for (int it = 0; it < dmax; it += 4) {
        int2 cc[4]; uint2 rv[4];
        #pragma unroll
        for (int q = 0; q < 4; ++q)
            cc[q] = (it + q < d) ? ucv[s + it + q] : cz;
        #pragma unroll
        for (int q = 0; q < 4; ++q)
            rv[q] = (it + q < d)
                  ? *(const uint2*)(esrc + (size_t)cc[q].x * CDIM + seg * 8) : uz;
        #pragma unroll
        for (int q = 0; q < 4; ++q)
            fma_rowV(acc, rv[q], __int_as_float(cc[q].y));
    }

    float uo[8];
    size_t ubase = (size_t)u * CDIM + seg * 8;
    if (uoldb) {
        uint4 pv = *(const uint4*)(uoldb + ubase);
        unpack8_bf(pv, uo);
    } else {
        float4 a = *(const float4*)(uoldf + ubase);
        float4 b = *(const float4*)(uoldf + ubase + 4);
        uo[0] = a.x; uo[1] = a.y; uo[2] = a.z; uo[3] = a.w;
        uo[4] = b.x; uo[5] = b.y; uo[6] = b.z; uo[7] = b.w;
    }
    float dts[N_FACTORS];
    #pragma unroll
    for (int f = 0; f < N_FACTORS; ++f) {
        const float4* lp = (const float4*)(latent + f * CDIM + seg * 8);
        float4 l0 = lp[0], l1 = lp[1];
        float p = uo[0] * l0.x + uo[1] * l0.y + uo[2] * l0.z + uo[3] * l0.w +
                  uo[4] * l1.x + uo[5] * l1.y + uo[6] * l1.z + uo[7] * l1.w;
        p += __shfl_xor(p, 1, 64);
        p += __shfl_xor(p, 2, 64);
        p += __shfl_xor(p, 4, 64);
        dts[f] = p;
    }
    float m = fmaxf(fmaxf(dts[0], dts[1]), fmaxf(dts[2], dts[3]));
    float e0 = __expf(dts[0] - m), e1 = __expf(dts[1] - m);
    float e2 = __expf(dts[2] - m), e3 = __expf(dts[3] - m);
    float inv_ssum = 1.0f / (e0 + e1 + e2 + e3);
    e0 *= inv_ssum; e1 *= inv_ssum; e2 *= inv_ssum; e3 *= inv_ssum;

    const float4* d0p = (const float4*)(dw + 0 * CDIM + seg * 8);
    const float4* d1p = (const float4*)(dw + 1 * CDIM + seg * 8);
    const float4* d2p = (const float4*)(dw + 2 * CDIM + seg * 8);
    const float4* d3p = (const float4*)(dw + 3 * CDIM + seg * 8);
    float4 ga0 = d0p[0], ga1 = d0p[1];
    float4 gb0 = d1p[0], gb1 = d1p[1];
    float4 gc0 = d2p[0], gc1 = d2p[1];
    float4 gd0 = d3p[0], gd1 = d3p[1];
    float g[8];
    g[0] = e0 * ga0.x + e1 * gb0.x + e2 * gc0.x + e3 * gd0.x;
    g[1] = e0 * ga0.y + e1 * gb0.y + e2 * gc0.y + e3 * gd0.y;
    g[2] = e0 * ga0.z + e1 * gb0.z + e2 * gc0.z + e3 * gd0.z;
    g[3] = e0 * ga0.w + e1 * gb0.w + e2 * gc0.w + e3 * gd0.w;
    g[4] = e0 * ga1.x + e1 * gb1.x + e2 * gc1.x + e3 * gd1.x;
    g[5] = e0 * ga1.y + e1 * gb1.y + e2 * gc1.y + e3 * gd1.y;
    g[6] = e0 * ga1.z + e1 * gb1.z + e2 * gc1.z + e3 * gd1.z;
    g[7] = e0 * ga1.w + e1 * gb1.w + e2 * gc1.w + e3 * gd1.w;

    float ssq = 0.0f;
    #pragma unroll
    for (int k = 0; k < 8; ++k) {
        acc[k] = acc[k] * (1.0f + g[k]);
        ssq += acc[k] * acc[k];
    }
    ssq += __shfl_xor(ssq, 1, 64);
    ssq += __shfl_xor(ssq, 2, 64);
    ssq += __shfl_xor(ssq, 4, 64);
    float rn = 1.0f / fmaxf(sqrtf(ssq), 1e-12f);
    #pragma unroll
    for (int k = 0; k < 8; ++k) acc[k] *= rn;

    if (!last) {
        *(uint4*)(unew + ubase) = pack8_bf(acc);
    } else {
        float4 a = *(const float4*)(uemb0 + ubase);
        float4 b = *(const float4*)(uemb0 + ubase + 4);
        float4 r0, r1;
        r0.x = a.x + uo[0] + acc[0]; r0.y = a.y + uo[1] + acc[1];
        r0.z = a.z + uo[2] + acc[2]; r0.w = a.w + uo[3] + acc[3];
        r1.x = b.x + uo[4] + acc[4]; r1.y = b.y + uo[5] + acc[5];
        r1.z = b.z + uo[6] + acc[6]; r1.w = b.w + uo[7] + acc[7];
        *(float4*)(ures + ubase) = r0;
        *(float4*)(ures + ubase + 4) = r1;
    }
}

// user blocks first (2x work/wave: deg~10 vs ~5) -> longest-work-first schedule
__global__ __launch_bounds__(256, 8) void hop_kernel(const u8* __restrict__ e_src,
                                                  const int2* __restrict__ permE,
                                                  const int* __restrict__ epk,
                                                  const float* __restrict__ weight,
                                                  const float* __restrict__ entity_emb,
                                                  u8* __restrict__ eA,
                                                  float* __restrict__ eres,
                                                  const float* __restrict__ uoldf,
                                                  const u16* __restrict__ uoldb,
                                                  const int2* __restrict__ permU,
                                                  const int2* __restrict__ ucv,
                                                  const float* __restrict__ latent,
                                                  const float* __restrict__ dw,
                                                  const float* __restrict__ user_emb,
                                                  u16* __restrict__ uA,
                                                  float* __restrict__ ures,
                                                  int last) {
    int bid = blockIdx.x;
    int wave = threadIdx.x >> 6;
    if (bid < USER_BLOCKS) {
        dev_user_hop(bid * 4 + wave, uoldf, uoldb, e_src, permU, ucv,
                     latent, dw, user_emb, uA, ures, last);
    } else {
        dev_kg_hop((bid - USER_BLOCKS) * 4 + wave, e_src, permE, epk, weight,
                   entity_emb, eA, eres, last);
    }
}

static inline size_t align16(size_t x) { return (x + 15) & ~(size_t)15; }

extern "C" void kernel_launch(void* const* d_in, const int* in_sizes, int n_in,
                              void* d_out, int out_size, void* d_ws, size_t ws_size,
                              hipStream_t stream) {
    const float* user_emb   = (const float*)d_in[0];
    const float* entity_emb = (const float*)d_in[1];
    const float* latent_emb = (const float*)d_in[2];
    const float* weight     = (const float*)d_in[3];
    const float* att        = (const float*)d_in[4];
    const int*   edge_index = (const int*)d_in[5];
    const int*   edge_type  = (const int*)d_in[6];
    const int*   inter_rows = (const int*)d_in[7];
    const int*   inter_cols = (const int*)d_in[8];
    const float* inter_vals = (const float*)d_in[9];

    float* eres = (float*)d_out;
    float* ures = eres + (size_t)N_ENTITIES * CDIM;
    float* cor  = ures + (size_t)N_USERS * CDIM;

    char* ws = (char*)d_ws;
    u8*    ef8   = (u8*)ws;   ws += align16(sizeof(u8) * (size_t)N_ENTITIES * CDIM);
    u8*    eA    = (u8*)ws;   ws += align16(sizeof(u8) * (size_t)N_ENTITIES * CDIM);
    u16*   uA    = (u16*)ws;  ws += align16(sizeof(u16) * (size_t)N_USERS * CDIM);
    int*   epk   = (int*)ws;  ws += align16(sizeof(int) * (size_t)NBE * CAPE);
    int2*  ucv   = (int2*)ws; ws += align16(sizeof(int2) * (size_t)NBU * CAPU);
    int*   bine  = (int*)ws;  ws += align16(sizeof(int) * (size_t)NBE * CAPE);
    int2*  binu  = (int2*)ws; ws += align16(sizeof(int2) * (size_t)NBU * CAPU);
    int2*  einfo = (int2*)ws; ws += align16(sizeof(int2) * N_ENTITIES);
    int2*  uinfo = (int2*)ws; ws += align16(sizeof(int2) * N_USERS);
    int*   ctrs  = (int*)ws;  ws += align16(sizeof(int) * 768);
    int2*  permE = (int2*)ws; ws += align16(sizeof(int2) * N_ENTITIES);
    int2*  permU = (int2*)ws; ws += align16(sizeof(int2) * N_USERS);
    float* dw    = (float*)ws; ws += align16(sizeof(float) * N_FACTORS * CDIM);

    int* zce   = ctrs;          // 256
    int* zcu   = ctrs + 256;    // 256
    int* dbinE = ctrs + 512;    // 64
    int* dbinU = ctrs + 576;    // 64
    int* zdegE = ctrs + 640;    // 64
    int* zdegU = ctrs + 704;    // 64

    const int* head = edge_index;
    const int* tail = edge_index + N_EDGES;

    (void)hipMemsetAsync(ctrs, 0, sizeof(int) * 768, stream);

    prep_kernel<<<GCVT + 2 * GA + 1, 256, 0, stream>>>(
        entity_emb, ef8, head, tail, edge_type,
        inter_rows, inter_cols, inter_vals,
        zce, zcu, bine, binu, att, weight, dw, cor);
    build_kernel<<<NBE + NBU, 256, 0, stream>>>(zce, zcu, bine, binu,
                                                einfo, epk, uinfo, ucv, dbinE, dbinU);
    perm_kernel<<<GPE + GPU_, 256, 0, stream>>>(einfo, uinfo, dbinE, dbinU,
                                                zdegE, zdegU, permE, permU);

    // hop 0: gather from ef8; write fp8 eA + bf16 uA
    hop_kernel<<<USER_BLOCKS + KG_BLOCKS, 256, 0, stream>>>(
        ef8, permE, epk, weight, entity_emb, eA, eres,
        user_emb, (const u16*)nullptr, permU, ucv, latent_emb, dw, user_emb, uA, ures, 0);
    // hop 1: gather from eA; write res = emb0 + o0 + o1
    hop_kernel<<<USER_BLOCKS + KG_BLOCKS, 256, 0, stream>>>(
        eA, permE, epk, weight, entity_emb, (u8*)nullptr, eres,
        (const float*)nullptr, uA, permU, ucv, latent_emb, dw, user_emb, (u16*)nullptr, ures, 1);
}